// Round 8
// baseline (1428.521 us; speedup 1.0000x reference)
//
#include <hip/hip_runtime.h>
#include <math.h>

#define E_EDGES 8192
#define D_FEAT 2048
#define K2 4096   // 2*D
#define H_DIM 128
#define N_NODES 100000
#define SIM_TH 0.7f
#define NSLOTS (2 * E_EDGES)   // 16384 compact slots

// ---------------------------------------------------------------------------
// Kernel 1: cosine similarity per edge. One wave (64 lanes) per edge.
// ---------------------------------------------------------------------------
__global__ __launch_bounds__(256) void sim_kernel(const float* __restrict__ xf,
                                                  const float* __restrict__ yf,
                                                  float* __restrict__ sim) {
    int gid  = blockIdx.x * blockDim.x + threadIdx.x;
    int wave = gid >> 6;
    int lane = threadIdx.x & 63;
    if (wave >= E_EDGES) return;
    const float4* xp = (const float4*)(xf + (size_t)wave * D_FEAT);
    const float4* yp = (const float4*)(yf + (size_t)wave * D_FEAT);
    float dot = 0.f, xx = 0.f, yy = 0.f;
#pragma unroll
    for (int j = 0; j < 8; ++j) {
        float4 a = xp[lane + j * 64];
        float4 b = yp[lane + j * 64];
        dot += a.x * b.x + a.y * b.y + a.z * b.z + a.w * b.w;
        xx  += a.x * a.x + a.y * a.y + a.z * a.z + a.w * a.w;
        yy  += b.x * b.x + b.y * b.y + b.z * b.z + b.w * b.w;
    }
#pragma unroll
    for (int off = 32; off; off >>= 1) {
        dot += __shfl_xor(dot, off);
        xx  += __shfl_xor(xx, off);
        yy  += __shfl_xor(yy, off);
    }
    if (lane == 0) {
        float nx = fmaxf(sqrtf(xx), 1e-8f);
        float ny = fmaxf(sqrtf(yy), 1e-8f);
        sim[wave] = dot / (nx * ny);
    }
}

// ---------------------------------------------------------------------------
// Kernel 2: init fo (=INT_MAX), orig (=-1), and zero w output.
// ---------------------------------------------------------------------------
__global__ void initmap_kernel(int* __restrict__ fo, int* __restrict__ orig,
                               float* __restrict__ wout) {
    int i = blockIdx.x * blockDim.x + threadIdx.x;
    if (i < N_NODES) fo[i] = 0x7FFFFFFF;
    if (i < NSLOTS)  orig[i] = -1;
    if (i < E_EDGES) wout[i] = 0.f;
}

// ---------------------------------------------------------------------------
// Kernel 3: claim compact slot = first occurrence index in x0,y0,x1,y1,...
// ---------------------------------------------------------------------------
__global__ void claim_kernel(const int* __restrict__ x_idx, const int* __restrict__ y_idx,
                             int* __restrict__ fo) {
    int i = blockIdx.x * blockDim.x + threadIdx.x;
    if (i >= NSLOTS) return;
    int e = i >> 1;
    int v = (i & 1) ? y_idx[e] : x_idx[e];
    atomicMin(&fo[v], i);
}

// ---------------------------------------------------------------------------
// Kernel 4: orig[slot] = node for claimed slots.
// ---------------------------------------------------------------------------
__global__ void orig_kernel(const int* __restrict__ x_idx, const int* __restrict__ y_idx,
                            const int* __restrict__ fo, int* __restrict__ orig) {
    int i = blockIdx.x * blockDim.x + threadIdx.x;
    if (i >= NSLOTS) return;
    int e = i >> 1;
    int v = (i & 1) ? y_idx[e] : x_idx[e];
    if (fo[v] == i) orig[i] = v;
}

// ---------------------------------------------------------------------------
// Kernel 5: order-preserving compaction of masked edges into records
//           rec = {cx, cy, eidx, (w filled later by gate)} + 4 zero pads.
// ---------------------------------------------------------------------------
__global__ __launch_bounds__(256) void maskscan_kernel(
        const int* __restrict__ x_idx, const int* __restrict__ y_idx,
        const int* __restrict__ fo, const float* __restrict__ sim,
        int4* __restrict__ rec, int* __restrict__ nmask) {
    __shared__ int partial[256];
    int t = threadIdx.x;
    int cnt = 0;
    for (int j = 0; j < 32; ++j) {
        int e = t * 32 + j;
        cnt += (sim[e] >= SIM_TH) ? 1 : 0;
    }
    partial[t] = cnt;
    __syncthreads();
    for (int off = 1; off < 256; off <<= 1) {
        int mine  = partial[t];
        int other = (t >= off) ? partial[t - off] : 0;
        __syncthreads();
        partial[t] = mine + other;
        __syncthreads();
    }
    int pos = partial[t] - cnt;
    if (t == 255) {
        int nn = partial[255];
        *nmask = nn;
        for (int j = 0; j < 4; ++j) rec[nn + j] = make_int4(0, 0, 0, 0);
    }
    for (int j = 0; j < 32; ++j) {
        int e = t * 32 + j;
        if (sim[e] >= SIM_TH) {
            int4 r;
            r.x = fo[x_idx[e]];
            r.y = fo[y_idx[e]];
            r.z = e;
            r.w = 0;
            rec[pos++] = r;
        }
    }
}

// ---------------------------------------------------------------------------
// Kernel 6: gate MLP over MASKED edges only (gathered rows).
// ---------------------------------------------------------------------------
#define BM 32
#define BK 32
#define SWZ(r, c) ((c) ^ ((((r) >> 2) & 7) << 2))

__global__ __launch_bounds__(256) void gate_kernel(
        const float* __restrict__ xf, const float* __restrict__ yf,
        const float* __restrict__ W1, const float* __restrict__ b1,
        const float* __restrict__ W2, const float* __restrict__ b2,
        int4* __restrict__ rec, const int* __restrict__ nmask,
        float* __restrict__ wout) {
    __shared__ float As[BM][BK];
    __shared__ float Bs[H_DIM][BK];
    __shared__ float red[BM][33];
    __shared__ int   elds[BM];

    int n  = *nmask;
    int b0 = blockIdx.x * BM;
    if (b0 >= n) return;

    int t  = threadIdx.x;
    if (t < BM) {
        int idx = b0 + t;
        elds[t] = (idx < n) ? rec[idx].z : rec[b0].z;
    }
    __syncthreads();

    int te = t >> 5;
    int tn = t & 31;
    int n0 = tn * 4;

    float acc[4][4] = {};

    for (int k0 = 0; k0 < K2; k0 += BK) {
        const float* src = (k0 < D_FEAT) ? xf : yf;
        int kk0 = (k0 < D_FEAT) ? k0 : (k0 - D_FEAT);
        {
            int row = t >> 3;
            int c   = (t & 7) * 4;
            float4 v = *(const float4*)(src + (size_t)elds[row] * D_FEAT + kk0 + c);
            *(float4*)(&As[row][SWZ(row, c)]) = v;
        }
#pragma unroll
        for (int r = 0; r < 4; ++r) {
            int nn = (t >> 3) + r * 32;
            int c  = (t & 7) * 4;
            float4 v = *(const float4*)(W1 + (size_t)nn * K2 + k0 + c);
            *(float4*)(&Bs[nn][SWZ(nn, c)]) = v;
        }
        __syncthreads();
        int swzA = (te & 7) << 2;
        int swzB = (tn & 7) << 2;
#pragma unroll
        for (int kk = 0; kk < BK; kk += 4) {
            float4 av[4], bv[4];
#pragma unroll
            for (int i = 0; i < 4; ++i)
                av[i] = *(const float4*)(&As[te * 4 + i][kk ^ swzA]);
#pragma unroll
            for (int j = 0; j < 4; ++j)
                bv[j] = *(const float4*)(&Bs[n0 + j][kk ^ swzB]);
#pragma unroll
            for (int i = 0; i < 4; ++i)
#pragma unroll
                for (int j = 0; j < 4; ++j)
                    acc[i][j] += av[i].x * bv[j].x + av[i].y * bv[j].y +
                                 av[i].z * bv[j].z + av[i].w * bv[j].w;
        }
        __syncthreads();
    }

    float b1v[4], w2v[4];
#pragma unroll
    for (int j = 0; j < 4; ++j) { b1v[j] = b1[n0 + j]; w2v[j] = W2[n0 + j]; }
#pragma unroll
    for (int i = 0; i < 4; ++i) {
        float p = 0.f;
#pragma unroll
        for (int j = 0; j < 4; ++j) {
            float h = fmaxf(acc[i][j] + b1v[j], 0.f);
            p += h * w2v[j];
        }
        red[te * 4 + i][tn] = p;
    }
    __syncthreads();
    if (t < BM && b0 + t < n) {
        float s = 0.f;
#pragma unroll
        for (int c = 0; c < 32; ++c) s += red[t][c];
        float logit = s + b2[0];
        float attn  = 1.f / (1.f + expf(-logit));
        wout[elds[t]] = attn;
        ((int*)&rec[b0 + t])[3] = __float_as_int(attn);
    }
}

// ---------------------------------------------------------------------------
// Exact serial processing of one edge (deep-path fallback). Matches reference
// order: find(x)+compress, then find(y)+compress, then union.
// ---------------------------------------------------------------------------
__device__ __noinline__ void serial_edge2(int2* nd, const int* ri, int eidx) {
    int x = ri[eidx * 4 + 0], y = ri[eidx * 4 + 1];
    float w = __int_as_float(ri[eidx * 4 + 3]);
    int p, j;
    int rx = x;
    while ((p = nd[rx].x) != rx) rx = p;
    j = x;
    while ((p = nd[j].x) != rx) { nd[j].x = rx; j = p; }
    int ry = y;
    while ((p = nd[ry].x) != ry) ry = p;
    j = y;
    while ((p = nd[j].x) != ry) { nd[j].x = ry; j = p; }
    if (rx != ry) {
        float a = __int_as_float(nd[rx].y), b = __int_as_float(nd[ry].y);
        bool bx = a > b;
        int big = bx ? rx : ry, small = bx ? ry : rx;
        nd[small].x = big;
        nd[big].y = __float_as_int(bx ? (a + b * w) : (b + a * w));
    }
}

// ---------------------------------------------------------------------------
// Kernel 7: serial union-find in LDS — single lane, packed int2 records,
//   register paths, unrolled walk, PLUS one-edge-ahead prefetch of the
//   level-0 records with 4-compare validation:
//     - prefetch nd[x_{i+1}], nd[y_{i+1}] issued before edge i's writes
//     - stale iff node in {small_i, big_i} (hot path) or poison (compression
//       wrote / fallback ran) -> cheap conservative re-read, no false negatives
// ---------------------------------------------------------------------------
__global__ __launch_bounds__(256) void uf_kernel(
        const int4* __restrict__ rec, const int* __restrict__ nmask,
        const int* __restrict__ orig, const float* __restrict__ rin,
        int* __restrict__ gpar, float* __restrict__ grank) {
    extern __shared__ char smem[];
    int2* nd = (int2*)smem;    // 128 KB {parent, rank-bits}
    int* ndw = (int*)smem;
    int t = threadIdx.x;
    for (int c = t; c < NSLOTS; c += 256) {
        int o = orig[c];
        float r = (o >= 0) ? rin[o] : 1.0f;
        nd[c] = make_int2(c, __float_as_int(r));   // parent == arange
    }
    __syncthreads();

    if (t == 0) {
        const int n = *nmask;
        const int* ri = (const int*)rec;
        if (n > 0) {
            int4 ea = rec[0];
            int4 eb = rec[1];
            int x0 = ea.x, y0 = ea.y, w0 = ea.w;   // current edge
            int x1 = eb.x, y1 = eb.y, w1 = eb.w;   // next edge
            int2 pfx = nd[x0];                      // prefetch for edge 0
            int2 pfy = nd[y0];
            int wsm = -1, wbg = -1;
            bool poison = false;

            for (int i = 0; i < n; ++i) {
                int4 ec = rec[i + 2];              // global prefetch (pads)

                // ---- validate / resolve current level-0 records ----
                bool badx = poison | (x0 == wsm) | (x0 == wbg);
                bool bady = poison | (y0 == wsm) | (y0 == wbg);
                int2 px = pfx, py = pfy;
                if (__builtin_expect(badx, 0)) px = nd[x0];
                if (__builtin_expect(bady, 0)) py = nd[y0];

                // ---- prefetch next edge's level-0 (pre-write of edge i) ----
                pfx = nd[x1];
                pfy = nd[y1];

                int x = x0, y = y0;
                float wi = __int_as_float(w0);
                bool fx = (px.x == x), fy = (py.x == y);
                int rx = x, ry = y;
                int kxb = px.y, kyb = py.y;        // rank bits at root
                bool ok = true, comp = false;

                if (!(fx && fy)) {
                    int cx1 = px.x, cy1 = py.x;    // distance-1 nodes
                    bool wx0 = false, wx1f = false, wy0 = false, wy1f = false;
                    // ---- round 2 ----
                    int ax = fx ? rx : cx1, ay = fy ? ry : cy1;
                    int2 qx = nd[ax];
                    int2 qy = nd[ay];
                    int cx2 = qx.x, cy2 = qy.x;
                    if (!fx && qx.x == ax) { rx = ax; kxb = qx.y; fx = true; }   // d=1
                    if (!fy && qy.x == ay) { ry = ay; kyb = qy.y; fy = true; }
                    if (!(fx && fy)) {
                        // ---- round 3 ----
                        int bx_ = fx ? rx : cx2, by_ = fy ? ry : cy2;
                        int2 ux = nd[bx_];
                        int2 uy = nd[by_];
                        int cx3 = ux.x, cy3 = uy.x;
                        if (!fx && ux.x == bx_) { rx = bx_; kxb = ux.y; fx = true; wx0 = true; }  // d=2
                        if (!fy && uy.x == by_) { ry = by_; kyb = uy.y; fy = true; wy0 = true; }
                        if (!(fx && fy)) {
                            // ---- round 4 ----
                            int gx = fx ? rx : cx3, gy = fy ? ry : cy3;
                            int2 vx = nd[gx];
                            int2 vy = nd[gy];
                            if (!fx && vx.x == gx) { rx = gx; kxb = vx.y; fx = true; wx0 = true; wx1f = true; }  // d=3
                            if (!fy && vy.x == gy) { ry = gy; kyb = vy.y; fy = true; wy0 = true; wy1f = true; }
                            if (!(fx && fy)) { serial_edge2(nd, ri, i); ok = false; }   // deep
                        }
                    }
                    if (ok) {
                        // compression: changed writes only (value-preserving skipped)
                        if (wx0)  ndw[x * 2]   = rx;
                        if (wx1f) ndw[cx1 * 2] = rx;
                        if (wy0)  ndw[y * 2]   = ry;
                        if (wy1f) ndw[cy1 * 2] = ry;
                        comp = wx0 | wy0;
                    }
                }

                int nsm = -1, nbg = -1;
                if (ok && rx != ry) {
                    float kx = __int_as_float(kxb), ky = __int_as_float(kyb);
                    bool bx = kx > ky;
                    int big = bx ? rx : ry, small = bx ? ry : rx;
                    float nr = bx ? (kx + ky * wi) : (ky + kx * wi);
                    ndw[small * 2]   = big;
                    ndw[big * 2 + 1] = __float_as_int(nr);
                    nsm = small; nbg = big;
                }

                poison = (!ok) | comp;
                wsm = nsm; wbg = nbg;
                x0 = x1; y0 = y1; w0 = w1;
                x1 = ec.x; y1 = ec.y; w1 = ec.w;
            }
        }
    }
    __syncthreads();
    for (int c = t; c < NSLOTS; c += 256) {
        int2 v = nd[c];
        gpar[c] = v.x;
        grank[c] = __int_as_float(v.y);
    }
}

// ---------------------------------------------------------------------------
// Kernel 8: finalize — per node, claimed -> compact result, else input copy.
// ---------------------------------------------------------------------------
__global__ void finalize_kernel(const int* __restrict__ pin, const float* __restrict__ rin,
                                const int* __restrict__ fo, const int* __restrict__ orig,
                                const int* __restrict__ gpar, const float* __restrict__ grank,
                                float* __restrict__ pout, float* __restrict__ rout) {
    int i = blockIdx.x * blockDim.x + threadIdx.x;
    if (i >= N_NODES) return;
    int c = fo[i];
    float pv, rv;
    if (c != 0x7FFFFFFF) {
        pv = (float)orig[gpar[c]];
        rv = grank[c];
    } else {
        pv = (float)pin[i];
        rv = rin[i];
    }
    pout[i] = pv;
    rout[i] = rv;
}

// ---------------------------------------------------------------------------
extern "C" void kernel_launch(void* const* d_in, const int* in_sizes, int n_in,
                              void* d_out, int out_size, void* d_ws, size_t ws_size,
                              hipStream_t stream) {
    const int*   x_idx = (const int*)d_in[0];
    const int*   y_idx = (const int*)d_in[1];
    const float* xf    = (const float*)d_in[2];
    const float* yf    = (const float*)d_in[3];
    const float* W1    = (const float*)d_in[4];
    const float* b1    = (const float*)d_in[5];
    const float* W2    = (const float*)d_in[6];
    const float* b2    = (const float*)d_in[7];
    const int*   pin   = (const int*)d_in[8];
    const float* rin   = (const float*)d_in[9];

    float* out   = (float*)d_out;
    float* w_out = out;                        // [E]
    float* pout  = out + E_EDGES;              // [N]
    float* rout  = out + E_EDGES + N_NODES;    // [N]

    char* ws = (char*)d_ws;
    float* sim_ws = (float*)(ws + 0);          //  32768 B
    int*   fo     = (int*)  (ws + 32768);      // 400000 B
    int*   orig   = (int*)  (ws + 432768);     //  65536 B
    int4*  rec    = (int4*) (ws + 498304);     // (E+4)*16 = 131136 B
    int*   nmask  = (int*)  (ws + 629440);     //     64 B
    int*   gpar   = (int*)  (ws + 629504);     //  65536 B
    float* grank  = (float*)(ws + 695040);     //  65536 B -> total 760576 B

    // 1) cosine sim
    sim_kernel<<<(E_EDGES * 64) / 256, 256, 0, stream>>>(xf, yf, sim_ws);
    // 2) compact-id mapping + zero w
    int g = (N_NODES + 255) / 256;
    initmap_kernel<<<g, 256, 0, stream>>>(fo, orig, w_out);
    claim_kernel<<<NSLOTS / 256, 256, 0, stream>>>(x_idx, y_idx, fo);
    orig_kernel<<<NSLOTS / 256, 256, 0, stream>>>(x_idx, y_idx, fo, orig);
    // 3) masked-edge compaction (records + padding)
    maskscan_kernel<<<1, 256, 0, stream>>>(x_idx, y_idx, fo, sim_ws, rec, nmask);
    // 4) gate MLP over masked edges only
    gate_kernel<<<E_EDGES / BM, 256, 0, stream>>>(xf, yf, W1, b1, W2, b2, rec, nmask, w_out);
    // 5) single-lane packed union-find in LDS, 1-ahead prefetch (128 KB)
    uf_kernel<<<1, 256, 131072, stream>>>(rec, nmask, orig, rin, gpar, grank);
    // 6) finalize outputs (base copy + compact scatter fused)
    finalize_kernel<<<g, 256, 0, stream>>>(pin, rin, fo, orig, gpar, grank, pout, rout);
}

// Round 9
// 877.231 us; speedup vs baseline: 1.6284x; 1.6284x over previous
//
#include <hip/hip_runtime.h>
#include <math.h>

#define E_EDGES 8192
#define D_FEAT 2048
#define K2 4096   // 2*D
#define H_DIM 128
#define N_NODES 100000
#define SIM_TH 0.7f
#define NSLOTS (2 * E_EDGES)   // 16384 compact slots
#define FRESH_FLAG (1 << 30)

// ---------------------------------------------------------------------------
// Kernel 1: cosine similarity per edge. One wave (64 lanes) per edge.
// ---------------------------------------------------------------------------
__global__ __launch_bounds__(256) void sim_kernel(const float* __restrict__ xf,
                                                  const float* __restrict__ yf,
                                                  float* __restrict__ sim) {
    int gid  = blockIdx.x * blockDim.x + threadIdx.x;
    int wave = gid >> 6;
    int lane = threadIdx.x & 63;
    if (wave >= E_EDGES) return;
    const float4* xp = (const float4*)(xf + (size_t)wave * D_FEAT);
    const float4* yp = (const float4*)(yf + (size_t)wave * D_FEAT);
    float dot = 0.f, xx = 0.f, yy = 0.f;
#pragma unroll
    for (int j = 0; j < 8; ++j) {
        float4 a = xp[lane + j * 64];
        float4 b = yp[lane + j * 64];
        dot += a.x * b.x + a.y * b.y + a.z * b.z + a.w * b.w;
        xx  += a.x * a.x + a.y * a.y + a.z * a.z + a.w * a.w;
        yy  += b.x * b.x + b.y * b.y + b.z * b.z + b.w * b.w;
    }
#pragma unroll
    for (int off = 32; off; off >>= 1) {
        dot += __shfl_xor(dot, off);
        xx  += __shfl_xor(xx, off);
        yy  += __shfl_xor(yy, off);
    }
    if (lane == 0) {
        float nx = fmaxf(sqrtf(xx), 1e-8f);
        float ny = fmaxf(sqrtf(yy), 1e-8f);
        sim[wave] = dot / (nx * ny);
    }
}

// ---------------------------------------------------------------------------
// Kernel 2: init fo (=INT_MAX), orig (=-1), fom (=INT_MAX), zero w output.
// ---------------------------------------------------------------------------
__global__ void initmap_kernel(int* __restrict__ fo, int* __restrict__ orig,
                               int* __restrict__ fom, float* __restrict__ wout) {
    int i = blockIdx.x * blockDim.x + threadIdx.x;
    if (i < N_NODES) fo[i] = 0x7FFFFFFF;
    if (i < NSLOTS)  { orig[i] = -1; fom[i] = 0x7FFFFFFF; }
    if (i < E_EDGES) wout[i] = 0.f;
}

// ---------------------------------------------------------------------------
// Kernel 3: claim compact slot = first occurrence index in x0,y0,x1,y1,...
// ---------------------------------------------------------------------------
__global__ void claim_kernel(const int* __restrict__ x_idx, const int* __restrict__ y_idx,
                             int* __restrict__ fo) {
    int i = blockIdx.x * blockDim.x + threadIdx.x;
    if (i >= NSLOTS) return;
    int e = i >> 1;
    int v = (i & 1) ? y_idx[e] : x_idx[e];
    atomicMin(&fo[v], i);
}

// ---------------------------------------------------------------------------
// Kernel 4: orig[slot] = node for claimed slots.
// ---------------------------------------------------------------------------
__global__ void orig_kernel(const int* __restrict__ x_idx, const int* __restrict__ y_idx,
                            const int* __restrict__ fo, int* __restrict__ orig) {
    int i = blockIdx.x * blockDim.x + threadIdx.x;
    if (i >= NSLOTS) return;
    int e = i >> 1;
    int v = (i & 1) ? y_idx[e] : x_idx[e];
    if (fo[v] == i) orig[i] = v;
}

// ---------------------------------------------------------------------------
// Kernel 5: order-preserving compaction of masked edges into records
//           rec = {cx, cy, eidx, (w filled later by gate)} + 4 zero pads.
// ---------------------------------------------------------------------------
__global__ __launch_bounds__(256) void maskscan_kernel(
        const int* __restrict__ x_idx, const int* __restrict__ y_idx,
        const int* __restrict__ fo, const float* __restrict__ sim,
        int4* __restrict__ rec, int* __restrict__ nmask) {
    __shared__ int partial[256];
    int t = threadIdx.x;
    int cnt = 0;
    for (int j = 0; j < 32; ++j) {
        int e = t * 32 + j;
        cnt += (sim[e] >= SIM_TH) ? 1 : 0;
    }
    partial[t] = cnt;
    __syncthreads();
    for (int off = 1; off < 256; off <<= 1) {
        int mine  = partial[t];
        int other = (t >= off) ? partial[t - off] : 0;
        __syncthreads();
        partial[t] = mine + other;
        __syncthreads();
    }
    int pos = partial[t] - cnt;
    if (t == 255) {
        int nn = partial[255];
        *nmask = nn;
        for (int j = 0; j < 4; ++j) rec[nn + j] = make_int4(0, 0, 0, 0);
    }
    for (int j = 0; j < 32; ++j) {
        int e = t * 32 + j;
        if (sim[e] >= SIM_TH) {
            int4 r;
            r.x = fo[x_idx[e]];
            r.y = fo[y_idx[e]];
            r.z = e;
            r.w = 0;
            rec[pos++] = r;
        }
    }
}

// ---------------------------------------------------------------------------
// Kernel 6: gate MLP over MASKED edges only (gathered rows).
// ---------------------------------------------------------------------------
#define BM 32
#define BK 32
#define SWZ(r, c) ((c) ^ ((((r) >> 2) & 7) << 2))

__global__ __launch_bounds__(256) void gate_kernel(
        const float* __restrict__ xf, const float* __restrict__ yf,
        const float* __restrict__ W1, const float* __restrict__ b1,
        const float* __restrict__ W2, const float* __restrict__ b2,
        int4* __restrict__ rec, const int* __restrict__ nmask,
        float* __restrict__ wout) {
    __shared__ float As[BM][BK];
    __shared__ float Bs[H_DIM][BK];
    __shared__ float red[BM][33];
    __shared__ int   elds[BM];

    int n  = *nmask;
    int b0 = blockIdx.x * BM;
    if (b0 >= n) return;

    int t  = threadIdx.x;
    if (t < BM) {
        int idx = b0 + t;
        elds[t] = (idx < n) ? rec[idx].z : rec[b0].z;
    }
    __syncthreads();

    int te = t >> 5;
    int tn = t & 31;
    int n0 = tn * 4;

    float acc[4][4] = {};

    for (int k0 = 0; k0 < K2; k0 += BK) {
        const float* src = (k0 < D_FEAT) ? xf : yf;
        int kk0 = (k0 < D_FEAT) ? k0 : (k0 - D_FEAT);
        {
            int row = t >> 3;
            int c   = (t & 7) * 4;
            float4 v = *(const float4*)(src + (size_t)elds[row] * D_FEAT + kk0 + c);
            *(float4*)(&As[row][SWZ(row, c)]) = v;
        }
#pragma unroll
        for (int r = 0; r < 4; ++r) {
            int nn = (t >> 3) + r * 32;
            int c  = (t & 7) * 4;
            float4 v = *(const float4*)(W1 + (size_t)nn * K2 + k0 + c);
            *(float4*)(&Bs[nn][SWZ(nn, c)]) = v;
        }
        __syncthreads();
        int swzA = (te & 7) << 2;
        int swzB = (tn & 7) << 2;
#pragma unroll
        for (int kk = 0; kk < BK; kk += 4) {
            float4 av[4], bv[4];
#pragma unroll
            for (int i = 0; i < 4; ++i)
                av[i] = *(const float4*)(&As[te * 4 + i][kk ^ swzA]);
#pragma unroll
            for (int j = 0; j < 4; ++j)
                bv[j] = *(const float4*)(&Bs[n0 + j][kk ^ swzB]);
#pragma unroll
            for (int i = 0; i < 4; ++i)
#pragma unroll
                for (int j = 0; j < 4; ++j)
                    acc[i][j] += av[i].x * bv[j].x + av[i].y * bv[j].y +
                                 av[i].z * bv[j].z + av[i].w * bv[j].w;
        }
        __syncthreads();
    }

    float b1v[4], w2v[4];
#pragma unroll
    for (int j = 0; j < 4; ++j) { b1v[j] = b1[n0 + j]; w2v[j] = W2[n0 + j]; }
#pragma unroll
    for (int i = 0; i < 4; ++i) {
        float p = 0.f;
#pragma unroll
        for (int j = 0; j < 4; ++j) {
            float h = fmaxf(acc[i][j] + b1v[j], 0.f);
            p += h * w2v[j];
        }
        red[te * 4 + i][tn] = p;
    }
    __syncthreads();
    if (t < BM && b0 + t < n) {
        float s = 0.f;
#pragma unroll
        for (int c = 0; c < 32; ++c) s += red[t][c];
        float logit = s + b2[0];
        float attn  = 1.f / (1.f + expf(-logit));
        wout[elds[t]] = attn;
        ((int*)&rec[b0 + t])[3] = __float_as_int(attn);
    }
}

// ---------------------------------------------------------------------------
// Kernel 6b: first-occurrence among MASKED edges (compact order), atomicMin
//            over slot index 2i (x) / 2i+1 (y).  Deterministic.
// ---------------------------------------------------------------------------
__global__ void freshmark_kernel(const int4* __restrict__ rec, const int* __restrict__ nmask,
                                 int* __restrict__ fom) {
    int i = blockIdx.x * blockDim.x + threadIdx.x;
    if (i >= *nmask) return;
    int4 r = rec[i];
    atomicMin(&fom[r.x], 2 * i);
    atomicMin(&fom[r.y], 2 * i + 1);
}

// ---------------------------------------------------------------------------
// Kernel 6c: flag fresh-fresh edges and precompute their union entirely:
//   both endpoints first-touched at this edge -> roots are themselves, ranks
//   are rin values -> rewrite rec as {small, big, z|FLAG, bits(new_rank)}.
//   Self-edge (cx==cy) fresh -> value-preserving writes {x, x, FLAG, r_x}.
// ---------------------------------------------------------------------------
__global__ void freshflag_kernel(int4* __restrict__ rec, const int* __restrict__ nmask,
                                 const int* __restrict__ fom, const int* __restrict__ orig,
                                 const float* __restrict__ rin) {
    int i = blockIdx.x * blockDim.x + threadIdx.x;
    if (i >= *nmask) return;
    int4 r = rec[i];
    int cx = r.x, cy = r.y;
    if (cx == cy) {
        if (fom[cx] == 2 * i) {
            float rx_ = rin[orig[cx]];
            rec[i] = make_int4(cx, cx, r.z | FRESH_FLAG, __float_as_int(rx_));
        }
        return;
    }
    if (fom[cx] == 2 * i && fom[cy] == 2 * i + 1) {
        float rx_ = rin[orig[cx]];
        float ry_ = rin[orig[cy]];
        float w   = __int_as_float(r.w);
        bool  bx  = rx_ > ry_;
        int big   = bx ? cx : cy;
        int small = bx ? cy : cx;
        float nr  = bx ? (rx_ + ry_ * w) : (ry_ + rx_ * w);
        rec[i] = make_int4(small, big, r.z | FRESH_FLAG, __float_as_int(nr));
    }
}

// ---------------------------------------------------------------------------
// Exact serial processing of one edge (deep-path fallback). Matches reference
// order: find(x)+compress, then find(y)+compress, then union.
// ---------------------------------------------------------------------------
__device__ __noinline__ void serial_edge2(int2* nd, const int* ri, int eidx) {
    int x = ri[eidx * 4 + 0], y = ri[eidx * 4 + 1];
    float w = __int_as_float(ri[eidx * 4 + 3]);
    int p, j;
    int rx = x;
    while ((p = nd[rx].x) != rx) rx = p;
    j = x;
    while ((p = nd[j].x) != rx) { nd[j].x = rx; j = p; }
    int ry = y;
    while ((p = nd[ry].x) != ry) ry = p;
    j = y;
    while ((p = nd[j].x) != ry) { nd[j].x = ry; j = p; }
    if (rx != ry) {
        float a = __int_as_float(nd[rx].y), b = __int_as_float(nd[ry].y);
        bool bx = a > b;
        int big = bx ? rx : ry, small = bx ? ry : rx;
        nd[small].x = big;
        nd[big].y = __float_as_int(bx ? (a + b * w) : (b + a * w));
    }
}

// ---------------------------------------------------------------------------
// Kernel 7: serial union-find in LDS — single lane, packed int2 records.
//   Fresh-fresh edges (~90%, precomputed by 6c): 2 LDS writes, no reads.
//   Others: R6's unrolled register-path walk; depth>3 -> exact fallback.
// ---------------------------------------------------------------------------
__global__ __launch_bounds__(256) void uf_kernel(
        const int4* __restrict__ rec, const int* __restrict__ nmask,
        const int* __restrict__ orig, const float* __restrict__ rin,
        int* __restrict__ gpar, float* __restrict__ grank) {
    extern __shared__ char smem[];
    int2* nd = (int2*)smem;    // 128 KB {parent, rank-bits}
    int* ndw = (int*)smem;
    int t = threadIdx.x;
    for (int c = t; c < NSLOTS; c += 256) {
        int o = orig[c];
        float r = (o >= 0) ? rin[o] : 1.0f;
        nd[c] = make_int2(c, __float_as_int(r));   // parent == arange
    }
    __syncthreads();

    if (t == 0) {
        const int n = *nmask;
        const int* ri = (const int*)rec;
        int4 e0 = rec[0];
        int4 e1 = rec[1];
        for (int i = 0; i < n; ++i) {
            int4 e2 = rec[i + 2];                 // prefetch (4 zero pads)

            if (e0.z & FRESH_FLAG) {
                // ---- precomputed union: parent[small]=big, rank[big]=nr ----
                ndw[e0.x * 2]     = e0.y;
                ndw[e0.y * 2 + 1] = e0.w;
            } else {
                int x = e0.x, y = e0.y;
                float wi = __int_as_float(e0.w);

                // ---- round 1: read both level-0 records (overlapped) ----
                int2 px = nd[x];
                int2 py = nd[y];
                bool fx = (px.x == x), fy = (py.x == y);
                int rx = x, ry = y;
                int kxb = px.y, kyb = py.y;       // rank bits at root
                bool ok = true;

                if (!(fx && fy)) {
                    int cx1 = px.x, cy1 = py.x;   // distance-1 nodes
                    bool wx0 = false, wx1f = false, wy0 = false, wy1f = false;
                    // ---- round 2 ----
                    int ax = fx ? rx : cx1, ay = fy ? ry : cy1;
                    int2 qx = nd[ax];
                    int2 qy = nd[ay];
                    int cx2 = qx.x, cy2 = qy.x;
                    if (!fx && qx.x == ax) { rx = ax; kxb = qx.y; fx = true; }   // d=1
                    if (!fy && qy.x == ay) { ry = ay; kyb = qy.y; fy = true; }
                    if (!(fx && fy)) {
                        // ---- round 3 ----
                        int bx_ = fx ? rx : cx2, by_ = fy ? ry : cy2;
                        int2 ux = nd[bx_];
                        int2 uy = nd[by_];
                        int cx3 = ux.x, cy3 = uy.x;
                        if (!fx && ux.x == bx_) { rx = bx_; kxb = ux.y; fx = true; wx0 = true; }  // d=2
                        if (!fy && uy.x == by_) { ry = by_; kyb = uy.y; fy = true; wy0 = true; }
                        if (!(fx && fy)) {
                            // ---- round 4 ----
                            int gx = fx ? rx : cx3, gy = fy ? ry : cy3;
                            int2 vx = nd[gx];
                            int2 vy = nd[gy];
                            if (!fx && vx.x == gx) { rx = gx; kxb = vx.y; fx = true; wx0 = true; wx1f = true; }  // d=3
                            if (!fy && vy.x == gy) { ry = gy; kyb = vy.y; fy = true; wy0 = true; wy1f = true; }
                            if (!(fx && fy)) { serial_edge2(nd, ri, i); ok = false; }   // deep
                        }
                    }
                    if (ok) {
                        // compression: changed writes only (value-preserving skipped)
                        if (wx0)  ndw[x * 2]   = rx;
                        if (wx1f) ndw[cx1 * 2] = rx;
                        if (wy0)  ndw[y * 2]   = ry;
                        if (wy1f) ndw[cy1 * 2] = ry;
                    }
                }
                if (ok && rx != ry) {
                    float kx = __int_as_float(kxb), ky = __int_as_float(kyb);
                    bool bx = kx > ky;
                    int big = bx ? rx : ry, small = bx ? ry : rx;
                    float nr = bx ? (kx + ky * wi) : (ky + kx * wi);
                    ndw[small * 2]   = big;
                    ndw[big * 2 + 1] = __float_as_int(nr);
                }
            }
            e0 = e1; e1 = e2;
        }
    }
    __syncthreads();
    for (int c = t; c < NSLOTS; c += 256) {
        int2 v = nd[c];
        gpar[c] = v.x;
        grank[c] = __int_as_float(v.y);
    }
}

// ---------------------------------------------------------------------------
// Kernel 8: finalize — per node, claimed -> compact result, else input copy.
// ---------------------------------------------------------------------------
__global__ void finalize_kernel(const int* __restrict__ pin, const float* __restrict__ rin,
                                const int* __restrict__ fo, const int* __restrict__ orig,
                                const int* __restrict__ gpar, const float* __restrict__ grank,
                                float* __restrict__ pout, float* __restrict__ rout) {
    int i = blockIdx.x * blockDim.x + threadIdx.x;
    if (i >= N_NODES) return;
    int c = fo[i];
    float pv, rv;
    if (c != 0x7FFFFFFF) {
        pv = (float)orig[gpar[c]];
        rv = grank[c];
    } else {
        pv = (float)pin[i];
        rv = rin[i];
    }
    pout[i] = pv;
    rout[i] = rv;
}

// ---------------------------------------------------------------------------
extern "C" void kernel_launch(void* const* d_in, const int* in_sizes, int n_in,
                              void* d_out, int out_size, void* d_ws, size_t ws_size,
                              hipStream_t stream) {
    const int*   x_idx = (const int*)d_in[0];
    const int*   y_idx = (const int*)d_in[1];
    const float* xf    = (const float*)d_in[2];
    const float* yf    = (const float*)d_in[3];
    const float* W1    = (const float*)d_in[4];
    const float* b1    = (const float*)d_in[5];
    const float* W2    = (const float*)d_in[6];
    const float* b2    = (const float*)d_in[7];
    const int*   pin   = (const int*)d_in[8];
    const float* rin   = (const float*)d_in[9];

    float* out   = (float*)d_out;
    float* w_out = out;                        // [E]
    float* pout  = out + E_EDGES;              // [N]
    float* rout  = out + E_EDGES + N_NODES;    // [N]

    char* ws = (char*)d_ws;
    float* sim_ws = (float*)(ws + 0);          //  32768 B
    int*   fo     = (int*)  (ws + 32768);      // 400000 B
    int*   orig   = (int*)  (ws + 432768);     //  65536 B
    int4*  rec    = (int4*) (ws + 498304);     // (E+4)*16 = 131136 B
    int*   nmask  = (int*)  (ws + 629440);     //     64 B
    int*   gpar   = (int*)  (ws + 629504);     //  65536 B
    float* grank  = (float*)(ws + 695040);     //  65536 B -> total 760576 B
    int*   fom    = gpar;   // overlay: fom used BEFORE uf writes gpar

    // 1) cosine sim
    sim_kernel<<<(E_EDGES * 64) / 256, 256, 0, stream>>>(xf, yf, sim_ws);
    // 2) compact-id mapping + fom init + zero w
    int g = (N_NODES + 255) / 256;
    initmap_kernel<<<g, 256, 0, stream>>>(fo, orig, fom, w_out);
    claim_kernel<<<NSLOTS / 256, 256, 0, stream>>>(x_idx, y_idx, fo);
    orig_kernel<<<NSLOTS / 256, 256, 0, stream>>>(x_idx, y_idx, fo, orig);
    // 3) masked-edge compaction (records + padding)
    maskscan_kernel<<<1, 256, 0, stream>>>(x_idx, y_idx, fo, sim_ws, rec, nmask);
    // 4) gate MLP over masked edges only (fills rec.w = w bits)
    gate_kernel<<<E_EDGES / BM, 256, 0, stream>>>(xf, yf, W1, b1, W2, b2, rec, nmask, w_out);
    // 5) fresh-fresh precompute (masked first-occurrence -> full union known)
    freshmark_kernel<<<NSLOTS / 256, 256, 0, stream>>>(rec, nmask, fom);
    freshflag_kernel<<<NSLOTS / 256, 256, 0, stream>>>(rec, nmask, fom, orig, rin);
    // 6) serial union-find in LDS (fast path for fresh-fresh)
    uf_kernel<<<1, 256, 131072, stream>>>(rec, nmask, orig, rin, gpar, grank);
    // 7) finalize outputs (base copy + compact scatter fused)
    finalize_kernel<<<g, 256, 0, stream>>>(pin, rin, fo, orig, gpar, grank, pout, rout);
}

// Round 10
// 505.162 us; speedup vs baseline: 2.8278x; 1.7365x over previous
//
#include <hip/hip_runtime.h>
#include <math.h>

#define E_EDGES 8192
#define D_FEAT 2048
#define K2 4096   // 2*D
#define H_DIM 128
#define N_NODES 100000
#define SIM_TH 0.7f
#define NSLOTS (2 * E_EDGES)   // 16384 compact slots
#define SORTN 8192

// ---------------------------------------------------------------------------
// Kernel 1: cosine similarity per edge. One wave (64 lanes) per edge.
// ---------------------------------------------------------------------------
__global__ __launch_bounds__(256) void sim_kernel(const float* __restrict__ xf,
                                                  const float* __restrict__ yf,
                                                  float* __restrict__ sim) {
    int gid  = blockIdx.x * blockDim.x + threadIdx.x;
    int wave = gid >> 6;
    int lane = threadIdx.x & 63;
    if (wave >= E_EDGES) return;
    const float4* xp = (const float4*)(xf + (size_t)wave * D_FEAT);
    const float4* yp = (const float4*)(yf + (size_t)wave * D_FEAT);
    float dot = 0.f, xx = 0.f, yy = 0.f;
#pragma unroll
    for (int j = 0; j < 8; ++j) {
        float4 a = xp[lane + j * 64];
        float4 b = yp[lane + j * 64];
        dot += a.x * b.x + a.y * b.y + a.z * b.z + a.w * b.w;
        xx  += a.x * a.x + a.y * a.y + a.z * a.z + a.w * a.w;
        yy  += b.x * b.x + b.y * b.y + b.z * b.z + b.w * b.w;
    }
#pragma unroll
    for (int off = 32; off; off >>= 1) {
        dot += __shfl_xor(dot, off);
        xx  += __shfl_xor(xx, off);
        yy  += __shfl_xor(yy, off);
    }
    if (lane == 0) {
        float nx = fmaxf(sqrtf(xx), 1e-8f);
        float ny = fmaxf(sqrtf(yy), 1e-8f);
        sim[wave] = dot / (nx * ny);
    }
}

// ---------------------------------------------------------------------------
// Kernel 2: init fo (=INT_MAX), orig (=-1), zero w output.
// ---------------------------------------------------------------------------
__global__ void initmap_kernel(int* __restrict__ fo, int* __restrict__ orig,
                               float* __restrict__ wout) {
    int i = blockIdx.x * blockDim.x + threadIdx.x;
    if (i < N_NODES) fo[i] = 0x7FFFFFFF;
    if (i < NSLOTS)  orig[i] = -1;
    if (i < E_EDGES) wout[i] = 0.f;
}

// ---------------------------------------------------------------------------
// Kernel 3: claim compact slot = first occurrence index in x0,y0,x1,y1,...
// ---------------------------------------------------------------------------
__global__ void claim_kernel(const int* __restrict__ x_idx, const int* __restrict__ y_idx,
                             int* __restrict__ fo) {
    int i = blockIdx.x * blockDim.x + threadIdx.x;
    if (i >= NSLOTS) return;
    int e = i >> 1;
    int v = (i & 1) ? y_idx[e] : x_idx[e];
    atomicMin(&fo[v], i);
}

// ---------------------------------------------------------------------------
// Kernel 4: orig[slot] = node for claimed slots.
// ---------------------------------------------------------------------------
__global__ void orig_kernel(const int* __restrict__ x_idx, const int* __restrict__ y_idx,
                            const int* __restrict__ fo, int* __restrict__ orig) {
    int i = blockIdx.x * blockDim.x + threadIdx.x;
    if (i >= NSLOTS) return;
    int e = i >> 1;
    int v = (i & 1) ? y_idx[e] : x_idx[e];
    if (fo[v] == i) orig[i] = v;
}

// ---------------------------------------------------------------------------
// Kernel 5: order-preserving compaction of masked edges into records
//           rec = {cx, cy, eidx, (w filled later by gate)} + 4 zero pads.
// ---------------------------------------------------------------------------
__global__ __launch_bounds__(256) void maskscan_kernel(
        const int* __restrict__ x_idx, const int* __restrict__ y_idx,
        const int* __restrict__ fo, const float* __restrict__ sim,
        int4* __restrict__ rec, int* __restrict__ nmask) {
    __shared__ int partial[256];
    int t = threadIdx.x;
    int cnt = 0;
    for (int j = 0; j < 32; ++j) {
        int e = t * 32 + j;
        cnt += (sim[e] >= SIM_TH) ? 1 : 0;
    }
    partial[t] = cnt;
    __syncthreads();
    for (int off = 1; off < 256; off <<= 1) {
        int mine  = partial[t];
        int other = (t >= off) ? partial[t - off] : 0;
        __syncthreads();
        partial[t] = mine + other;
        __syncthreads();
    }
    int pos = partial[t] - cnt;
    if (t == 255) {
        int nn = partial[255];
        *nmask = nn;
        for (int j = 0; j < 4; ++j) rec[nn + j] = make_int4(0, 0, 0, 0);
    }
    for (int j = 0; j < 32; ++j) {
        int e = t * 32 + j;
        if (sim[e] >= SIM_TH) {
            int4 r;
            r.x = fo[x_idx[e]];
            r.y = fo[y_idx[e]];
            r.z = e;
            r.w = 0;
            rec[pos++] = r;
        }
    }
}

// ---------------------------------------------------------------------------
// Kernel 6: gate MLP over MASKED edges only (gathered rows).
// ---------------------------------------------------------------------------
#define BM 32
#define BK 32
#define SWZ(r, c) ((c) ^ ((((r) >> 2) & 7) << 2))

__global__ __launch_bounds__(256) void gate_kernel(
        const float* __restrict__ xf, const float* __restrict__ yf,
        const float* __restrict__ W1, const float* __restrict__ b1,
        const float* __restrict__ W2, const float* __restrict__ b2,
        int4* __restrict__ rec, const int* __restrict__ nmask,
        float* __restrict__ wout) {
    __shared__ float As[BM][BK];
    __shared__ float Bs[H_DIM][BK];
    __shared__ float red[BM][33];
    __shared__ int   elds[BM];

    int n  = *nmask;
    int b0 = blockIdx.x * BM;
    if (b0 >= n) return;

    int t  = threadIdx.x;
    if (t < BM) {
        int idx = b0 + t;
        elds[t] = (idx < n) ? rec[idx].z : rec[b0].z;
    }
    __syncthreads();

    int te = t >> 5;
    int tn = t & 31;
    int n0 = tn * 4;

    float acc[4][4] = {};

    for (int k0 = 0; k0 < K2; k0 += BK) {
        const float* src = (k0 < D_FEAT) ? xf : yf;
        int kk0 = (k0 < D_FEAT) ? k0 : (k0 - D_FEAT);
        {
            int row = t >> 3;
            int c   = (t & 7) * 4;
            float4 v = *(const float4*)(src + (size_t)elds[row] * D_FEAT + kk0 + c);
            *(float4*)(&As[row][SWZ(row, c)]) = v;
        }
#pragma unroll
        for (int r = 0; r < 4; ++r) {
            int nn = (t >> 3) + r * 32;
            int c  = (t & 7) * 4;
            float4 v = *(const float4*)(W1 + (size_t)nn * K2 + k0 + c);
            *(float4*)(&Bs[nn][SWZ(nn, c)]) = v;
        }
        __syncthreads();
        int swzA = (te & 7) << 2;
        int swzB = (tn & 7) << 2;
#pragma unroll
        for (int kk = 0; kk < BK; kk += 4) {
            float4 av[4], bv[4];
#pragma unroll
            for (int i = 0; i < 4; ++i)
                av[i] = *(const float4*)(&As[te * 4 + i][kk ^ swzA]);
#pragma unroll
            for (int j = 0; j < 4; ++j)
                bv[j] = *(const float4*)(&Bs[n0 + j][kk ^ swzB]);
#pragma unroll
            for (int i = 0; i < 4; ++i)
#pragma unroll
                for (int j = 0; j < 4; ++j)
                    acc[i][j] += av[i].x * bv[j].x + av[i].y * bv[j].y +
                                 av[i].z * bv[j].z + av[i].w * bv[j].w;
        }
        __syncthreads();
    }

    float b1v[4], w2v[4];
#pragma unroll
    for (int j = 0; j < 4; ++j) { b1v[j] = b1[n0 + j]; w2v[j] = W2[n0 + j]; }
#pragma unroll
    for (int i = 0; i < 4; ++i) {
        float p = 0.f;
#pragma unroll
        for (int j = 0; j < 4; ++j) {
            float h = fmaxf(acc[i][j] + b1v[j], 0.f);
            p += h * w2v[j];
        }
        red[te * 4 + i][tn] = p;
    }
    __syncthreads();
    if (t < BM && b0 + t < n) {
        float s = 0.f;
#pragma unroll
        for (int c = 0; c < 32; ++c) s += red[t][c];
        float logit = s + b2[0];
        float attn  = 1.f / (1.f + expf(-logit));
        wout[elds[t]] = attn;
        ((int*)&rec[b0 + t])[3] = __float_as_int(attn);
    }
}

// ---------------------------------------------------------------------------
// Kernel 7: connected-component labels of the masked-edge graph (compact ids).
//   Min-label propagation to fixpoint (LDS atomicMin, monotone, deterministic
//   final state = min node id per CC) + pointer jumping for fast convergence.
// ---------------------------------------------------------------------------
__global__ __launch_bounds__(1024) void label_kernel(
        const int4* __restrict__ rec, const int* __restrict__ nmask,
        int* __restrict__ lbl) {
    extern __shared__ int L[];        // NSLOTS labels + flag at L[NSLOTS]
    int t = threadIdx.x;
    int n = *nmask;
    for (int c = t; c < NSLOTS; c += 1024) L[c] = c;
    __syncthreads();
    for (;;) {
        if (t == 0) L[NSLOTS] = 0;
        __syncthreads();
        for (int e = t; e < n; e += 1024) {
            int4 r = rec[e];
            int a = L[r.x], b = L[r.y];
            if (a < b)      { atomicMin(&L[r.y], a); L[NSLOTS] = 1; }
            else if (b < a) { atomicMin(&L[r.x], b); L[NSLOTS] = 1; }
        }
        __syncthreads();
        if (!L[NSLOTS]) break;
        __syncthreads();
        // pointer jumping (owner-only writes; monotone)
        for (int c = t; c < NSLOTS; c += 1024) {
            int q  = L[c];
            int qq = L[q];
            if (qq < q) L[c] = qq;
        }
        __syncthreads();
    }
    __syncthreads();
    for (int c = t; c < NSLOTS; c += 1024) lbl[c] = L[c];
}

// ---------------------------------------------------------------------------
// Kernel 8: stable grouping of masked edges by CC label.
//   Bitonic sort of 8192 keys (label<<13 | edge_idx) in LDS; emit
//   srec[] = records in (label, edge-order) order, compStart[], ncomp.
// ---------------------------------------------------------------------------
__global__ __launch_bounds__(1024) void sortgroup_kernel(
        const int4* __restrict__ rec, const int* __restrict__ nmask,
        const int* __restrict__ lbl, int4* __restrict__ srec,
        int* __restrict__ compStart, int* __restrict__ ncompOut) {
    extern __shared__ char sm[];
    int2* a          = (int2*)sm;                        // 64 KB
    unsigned char* hd = (unsigned char*)(sm + 65536);    //  8 KB
    int* part        = (int*)(sm + 65536 + 8192);        //  4 KB
    int t = threadIdx.x;
    int n = *nmask;

    for (int i = t; i < SORTN; i += 1024) {
        int key = 0x7FFFFFFF;
        if (i < n) key = (lbl[rec[i].x] << 13) | i;
        a[i] = make_int2(key, i);
    }
    for (int k = 2; k <= SORTN; k <<= 1) {
        for (int j = k >> 1; j > 0; j >>= 1) {
            __syncthreads();
            for (int i = t; i < SORTN; i += 1024) {
                int ixj = i ^ j;
                if (ixj > i) {
                    int2 ai = a[i], aj = a[ixj];
                    bool up = ((i & k) == 0);
                    if ((ai.x > aj.x) == up) { a[i] = aj; a[ixj] = ai; }
                }
            }
        }
    }
    __syncthreads();
    // emit sorted records + head flags (label boundary)
    for (int i = t; i < SORTN; i += 1024) {
        int h = 0;
        if (i < n) {
            srec[i] = rec[a[i].y];
            int l  = a[i].x >> 13;
            int lp = (i == 0) ? -1 : (a[i - 1].x >> 13);
            h = (l != lp) ? 1 : 0;
        }
        hd[i] = (unsigned char)h;
    }
    __syncthreads();
    int base = t * 8;
    int s = 0;
#pragma unroll
    for (int q = 0; q < 8; ++q) s += hd[base + q];
    part[t] = s;
    __syncthreads();
    for (int off = 1; off < 1024; off <<= 1) {
        int mine  = part[t];
        int other = (t >= off) ? part[t - off] : 0;
        __syncthreads();
        part[t] = mine + other;
        __syncthreads();
    }
    int total = part[1023];
    int run = part[t] - s;            // exclusive prefix
#pragma unroll
    for (int q = 0; q < 8; ++q) {
        if (hd[base + q]) { compStart[run] = base + q; ++run; }
    }
    if (t == 0)    *ncompOut = total;
    if (t == 1023) compStart[total] = n;   // terminator
}

// ---------------------------------------------------------------------------
// Kernel 9: exact union-find, parallel over connected components.
//   Each lane serially processes its components' edges (in global edge order)
//   with the exact reference find+compress+union on LDS nd.  Different CCs
//   touch disjoint nodes -> no races, bit-identical to serial execution.
// ---------------------------------------------------------------------------
__global__ __launch_bounds__(256) void uf_kernel(
        const int4* __restrict__ srec, const int* __restrict__ ncompPtr,
        const int* __restrict__ compStart,
        const int* __restrict__ orig, const float* __restrict__ rin,
        int* __restrict__ gpar, float* __restrict__ grank) {
    extern __shared__ char smem[];
    int2* nd = (int2*)smem;    // 128 KB {parent, rank-bits}
    int* ndw = (int*)smem;
    int t = threadIdx.x;
    for (int c = t; c < NSLOTS; c += 256) {
        int o = orig[c];
        float r = (o >= 0) ? rin[o] : 1.0f;
        nd[c] = make_int2(c, __float_as_int(r));   // parent == arange
    }
    __syncthreads();

    int ncomp = *ncompPtr;
    for (int c = t; c < ncomp; c += 256) {
        int s  = compStart[c];
        int en = compStart[c + 1];
        for (int j = s; j < en; ++j) {
            int4 r = srec[j];
            int x = r.x, y = r.y;
            float wi = __int_as_float(r.w);
            int p;
            int rx = x;
            while ((p = ndw[rx * 2]) != rx) rx = p;
            int j2 = x;
            while ((p = ndw[j2 * 2]) != rx) { ndw[j2 * 2] = rx; j2 = p; }
            int ry = y;
            while ((p = ndw[ry * 2]) != ry) ry = p;
            j2 = y;
            while ((p = ndw[j2 * 2]) != ry) { ndw[j2 * 2] = ry; j2 = p; }
            if (rx != ry) {
                float ka = __int_as_float(ndw[rx * 2 + 1]);
                float kb = __int_as_float(ndw[ry * 2 + 1]);
                bool bx = ka > kb;
                int big = bx ? rx : ry, small = bx ? ry : rx;
                float nr = bx ? (ka + kb * wi) : (kb + ka * wi);
                ndw[small * 2]   = big;
                ndw[big * 2 + 1] = __float_as_int(nr);
            }
        }
    }
    __syncthreads();
    for (int c = t; c < NSLOTS; c += 256) {
        int2 v = nd[c];
        gpar[c] = v.x;
        grank[c] = __int_as_float(v.y);
    }
}

// ---------------------------------------------------------------------------
// Kernel 10: finalize — per node, claimed -> compact result, else input copy.
// ---------------------------------------------------------------------------
__global__ void finalize_kernel(const int* __restrict__ pin, const float* __restrict__ rin,
                                const int* __restrict__ fo, const int* __restrict__ orig,
                                const int* __restrict__ gpar, const float* __restrict__ grank,
                                float* __restrict__ pout, float* __restrict__ rout) {
    int i = blockIdx.x * blockDim.x + threadIdx.x;
    if (i >= N_NODES) return;
    int c = fo[i];
    float pv, rv;
    if (c != 0x7FFFFFFF) {
        pv = (float)orig[gpar[c]];
        rv = grank[c];
    } else {
        pv = (float)pin[i];
        rv = rin[i];
    }
    pout[i] = pv;
    rout[i] = rv;
}

// ---------------------------------------------------------------------------
extern "C" void kernel_launch(void* const* d_in, const int* in_sizes, int n_in,
                              void* d_out, int out_size, void* d_ws, size_t ws_size,
                              hipStream_t stream) {
    const int*   x_idx = (const int*)d_in[0];
    const int*   y_idx = (const int*)d_in[1];
    const float* xf    = (const float*)d_in[2];
    const float* yf    = (const float*)d_in[3];
    const float* W1    = (const float*)d_in[4];
    const float* b1    = (const float*)d_in[5];
    const float* W2    = (const float*)d_in[6];
    const float* b2    = (const float*)d_in[7];
    const int*   pin   = (const int*)d_in[8];
    const float* rin   = (const float*)d_in[9];

    float* out   = (float*)d_out;
    float* w_out = out;                        // [E]
    float* pout  = out + E_EDGES;              // [N]
    float* rout  = out + E_EDGES + N_NODES;    // [N]

    char* ws = (char*)d_ws;
    float* sim_ws  = (float*)(ws + 0);         //  32768 B
    int*   fo      = (int*)  (ws + 32768);     // 400000 B
    int*   orig    = (int*)  (ws + 432768);    //  65536 B
    int4*  rec     = (int4*) (ws + 498304);    // 131136 B  (8192+4 recs)
    int*   nmask   = (int*)  (ws + 629440);    //     64 B
    int*   gpar    = (int*)  (ws + 629504);    //  65536 B
    float* grank   = (float*)(ws + 695040);    //  65536 B
    int4*  srec    = (int4*) (ws + 760576);    // 131072 B
    int*   compSt  = (int*)  (ws + 891648);    //  32772 B (8193 ints)
    int*   ncomp   = (int*)  (ws + 924424);    //      4 B  -> total ~924 KB
    int*   lbl     = gpar;   // overlay: lbl consumed before uf writes gpar

    // 1) cosine sim
    sim_kernel<<<(E_EDGES * 64) / 256, 256, 0, stream>>>(xf, yf, sim_ws);
    // 2) compact-id mapping + zero w
    int g = (N_NODES + 255) / 256;
    initmap_kernel<<<g, 256, 0, stream>>>(fo, orig, w_out);
    claim_kernel<<<NSLOTS / 256, 256, 0, stream>>>(x_idx, y_idx, fo);
    orig_kernel<<<NSLOTS / 256, 256, 0, stream>>>(x_idx, y_idx, fo, orig);
    // 3) masked-edge compaction (records + padding)
    maskscan_kernel<<<1, 256, 0, stream>>>(x_idx, y_idx, fo, sim_ws, rec, nmask);
    // 4) gate MLP over masked edges only (fills rec.w)
    gate_kernel<<<E_EDGES / BM, 256, 0, stream>>>(xf, yf, W1, b1, W2, b2, rec, nmask, w_out);
    // 5) CC labels of masked-edge graph (deterministic min-label fixpoint)
    label_kernel<<<1, 1024, (NSLOTS + 1) * sizeof(int), stream>>>(rec, nmask, lbl);
    // 6) stable per-CC grouping (bitonic sort + boundaries)
    sortgroup_kernel<<<1, 1024, 65536 + 8192 + 4096, stream>>>(rec, nmask, lbl,
                                                               srec, compSt, ncomp);
    // 7) exact UF, parallel over components (LDS 128 KB)
    uf_kernel<<<1, 256, 131072, stream>>>(srec, ncomp, compSt, orig, rin, gpar, grank);
    // 8) finalize outputs (base copy + compact scatter fused)
    finalize_kernel<<<g, 256, 0, stream>>>(pin, rin, fo, orig, gpar, grank, pout, rout);
}

// Round 11
// 445.604 us; speedup vs baseline: 3.2058x; 1.1337x over previous
//
#include <hip/hip_runtime.h>
#include <math.h>

#define E_EDGES 8192
#define D_FEAT 2048
#define K2 4096   // 2*D
#define H_DIM 128
#define N_NODES 100000
#define SIM_TH 0.7f
#define NSLOTS (2 * E_EDGES)   // 16384 compact slots
#define SORTN 8192
#define GBM 16                 // gate edges per block

// ---------------------------------------------------------------------------
// Kernel 1: cosine similarity per edge. One wave (64 lanes) per edge.
// ---------------------------------------------------------------------------
__global__ __launch_bounds__(256) void sim_kernel(const float* __restrict__ xf,
                                                  const float* __restrict__ yf,
                                                  float* __restrict__ sim) {
    int gid  = blockIdx.x * blockDim.x + threadIdx.x;
    int wave = gid >> 6;
    int lane = threadIdx.x & 63;
    if (wave >= E_EDGES) return;
    const float4* xp = (const float4*)(xf + (size_t)wave * D_FEAT);
    const float4* yp = (const float4*)(yf + (size_t)wave * D_FEAT);
    float dot = 0.f, xx = 0.f, yy = 0.f;
#pragma unroll
    for (int j = 0; j < 8; ++j) {
        float4 a = xp[lane + j * 64];
        float4 b = yp[lane + j * 64];
        dot += a.x * b.x + a.y * b.y + a.z * b.z + a.w * b.w;
        xx  += a.x * a.x + a.y * a.y + a.z * a.z + a.w * a.w;
        yy  += b.x * b.x + b.y * b.y + b.z * b.z + b.w * b.w;
    }
#pragma unroll
    for (int off = 32; off; off >>= 1) {
        dot += __shfl_xor(dot, off);
        xx  += __shfl_xor(xx, off);
        yy  += __shfl_xor(yy, off);
    }
    if (lane == 0) {
        float nx = fmaxf(sqrtf(xx), 1e-8f);
        float ny = fmaxf(sqrtf(yy), 1e-8f);
        sim[wave] = dot / (nx * ny);
    }
}

// ---------------------------------------------------------------------------
// Kernel 2: init fo (=INT_MAX), orig (=-1), zero w output.
// ---------------------------------------------------------------------------
__global__ void initmap_kernel(int* __restrict__ fo, int* __restrict__ orig,
                               float* __restrict__ wout) {
    int i = blockIdx.x * blockDim.x + threadIdx.x;
    if (i < N_NODES) fo[i] = 0x7FFFFFFF;
    if (i < NSLOTS)  orig[i] = -1;
    if (i < E_EDGES) wout[i] = 0.f;
}

// ---------------------------------------------------------------------------
// Kernel 3: claim compact slot = first occurrence index in x0,y0,x1,y1,...
// ---------------------------------------------------------------------------
__global__ void claim_kernel(const int* __restrict__ x_idx, const int* __restrict__ y_idx,
                             int* __restrict__ fo) {
    int i = blockIdx.x * blockDim.x + threadIdx.x;
    if (i >= NSLOTS) return;
    int e = i >> 1;
    int v = (i & 1) ? y_idx[e] : x_idx[e];
    atomicMin(&fo[v], i);
}

// ---------------------------------------------------------------------------
// Kernel 4: orig[slot] = node for claimed slots.
// ---------------------------------------------------------------------------
__global__ void orig_kernel(const int* __restrict__ x_idx, const int* __restrict__ y_idx,
                            const int* __restrict__ fo, int* __restrict__ orig) {
    int i = blockIdx.x * blockDim.x + threadIdx.x;
    if (i >= NSLOTS) return;
    int e = i >> 1;
    int v = (i & 1) ? y_idx[e] : x_idx[e];
    if (fo[v] == i) orig[i] = v;
}

// ---------------------------------------------------------------------------
// Kernel 5: order-preserving compaction of masked edges into records
//           rec = {cx, cy, eidx, (w filled later by gate)} + 4 zero pads.
// ---------------------------------------------------------------------------
__global__ __launch_bounds__(256) void maskscan_kernel(
        const int* __restrict__ x_idx, const int* __restrict__ y_idx,
        const int* __restrict__ fo, const float* __restrict__ sim,
        int4* __restrict__ rec, int* __restrict__ nmask) {
    __shared__ int partial[256];
    int t = threadIdx.x;
    int cnt = 0;
    for (int j = 0; j < 32; ++j) {
        int e = t * 32 + j;
        cnt += (sim[e] >= SIM_TH) ? 1 : 0;
    }
    partial[t] = cnt;
    __syncthreads();
    for (int off = 1; off < 256; off <<= 1) {
        int mine  = partial[t];
        int other = (t >= off) ? partial[t - off] : 0;
        __syncthreads();
        partial[t] = mine + other;
        __syncthreads();
    }
    int pos = partial[t] - cnt;
    if (t == 255) {
        int nn = partial[255];
        *nmask = nn;
        for (int j = 0; j < 4; ++j) rec[nn + j] = make_int4(0, 0, 0, 0);
    }
    for (int j = 0; j < 32; ++j) {
        int e = t * 32 + j;
        if (sim[e] >= SIM_TH) {
            int4 r;
            r.x = fo[x_idx[e]];
            r.y = fo[y_idx[e]];
            r.z = e;
            r.w = 0;
            rec[pos++] = r;
        }
    }
}

// ---------------------------------------------------------------------------
// Kernel 6: gate MLP v2 over MASKED edges. fp32 GEMM M=n, N=128, K=4096.
//   GBM=16 edges/block (512-block grid -> all CUs), double-buffered staging
//   with async split (global->reg early, reg->LDS late), transposed B tile
//   (pitch 132, float2 reads, 2-way banks only).  Accumulation is a strictly
//   k-ascending fmaf chain per (edge,n); epilogue recomputed in the exact
//   legacy order from an h-buffer -> bit-identical outputs.
// ---------------------------------------------------------------------------
__global__ __launch_bounds__(256) void gate_kernel(
        const float* __restrict__ xf, const float* __restrict__ yf,
        const float* __restrict__ W1, const float* __restrict__ b1,
        const float* __restrict__ W2, const float* __restrict__ b2,
        int4* __restrict__ rec, const int* __restrict__ nmask,
        float* __restrict__ wout) {
    __shared__ float As[2][GBM][32];     //  4 KB
    __shared__ float Bs[2][32][132];     // 33 KB  (BsT: [k][n], pitch 132)
    __shared__ float hbuf[GBM][132];     //  8.25 KB
    __shared__ int   elds[GBM];

    int n  = *nmask;
    int b0 = blockIdx.x * GBM;
    if (b0 >= n) return;

    int t = threadIdx.x;
    if (t < GBM) {
        int idx = b0 + t;
        elds[t] = (idx < n) ? rec[idx].z : rec[b0].z;
    }
    __syncthreads();

    // staging assignments
    const int arow = t >> 3;            // 0..31 (A uses t<128 -> 0..15)
    const int acol = (t & 7) * 4;
    const int brow = t >> 3;            // W1 rows brow+32r
    const int bcol = (t & 7) * 4;       // k-offset in tile
    const bool aact = (t < 128);

    const float* xrow = xf + (size_t)(aact ? elds[arow] : elds[0]) * D_FEAT + acol;
    const float* yrow = yf + (size_t)(aact ? elds[arow] : elds[0]) * D_FEAT + acol;
    const float* w1p0 = W1 + (size_t)(brow +  0) * K2 + bcol;
    const float* w1p1 = W1 + (size_t)(brow + 32) * K2 + bcol;
    const float* w1p2 = W1 + (size_t)(brow + 64) * K2 + bcol;
    const float* w1p3 = W1 + (size_t)(brow + 96) * K2 + bcol;

    float4 aR, bR0, bR1, bR2, bR3;

    // ---- prologue: load + store tile 0 ----
    {
        aR  = *(const float4*)(xrow + 0);
        bR0 = *(const float4*)(w1p0 + 0);
        bR1 = *(const float4*)(w1p1 + 0);
        bR2 = *(const float4*)(w1p2 + 0);
        bR3 = *(const float4*)(w1p3 + 0);
        if (aact) *(float4*)(&As[0][arow][acol]) = aR;
        Bs[0][bcol + 0][brow +  0] = bR0.x; Bs[0][bcol + 1][brow +  0] = bR0.y;
        Bs[0][bcol + 2][brow +  0] = bR0.z; Bs[0][bcol + 3][brow +  0] = bR0.w;
        Bs[0][bcol + 0][brow + 32] = bR1.x; Bs[0][bcol + 1][brow + 32] = bR1.y;
        Bs[0][bcol + 2][brow + 32] = bR1.z; Bs[0][bcol + 3][brow + 32] = bR1.w;
        Bs[0][bcol + 0][brow + 64] = bR2.x; Bs[0][bcol + 1][brow + 64] = bR2.y;
        Bs[0][bcol + 2][brow + 64] = bR2.z; Bs[0][bcol + 3][brow + 64] = bR2.w;
        Bs[0][bcol + 0][brow + 96] = bR3.x; Bs[0][bcol + 1][brow + 96] = bR3.y;
        Bs[0][bcol + 2][brow + 96] = bR3.z; Bs[0][bcol + 3][brow + 96] = bR3.w;
    }
    __syncthreads();

    const int e0  = (t >> 5) * 2;       // this thread's 2 edge rows
    const int tnn = t & 31;             // n base: {2tnn, 2tnn+1, +64, +65}
    float acc[2][4] = {{0.f,0.f,0.f,0.f},{0.f,0.f,0.f,0.f}};

    const int NT = K2 / 32;             // 128 tiles
    for (int tile = 0; tile < NT; ++tile) {
        const int buf = tile & 1;
        // ---- issue next tile's global loads (latency hides under compute)
        if (tile + 1 < NT) {
            int k0 = (tile + 1) * 32;
            const float* ap = (k0 < D_FEAT) ? (xrow + k0) : (yrow + (k0 - D_FEAT));
            aR  = *(const float4*)ap;
            bR0 = *(const float4*)(w1p0 + k0);
            bR1 = *(const float4*)(w1p1 + k0);
            bR2 = *(const float4*)(w1p2 + k0);
            bR3 = *(const float4*)(w1p3 + k0);
        }
        // ---- compute current tile ----
#pragma unroll
        for (int kk = 0; kk < 32; kk += 4) {
            float4 a0 = *(const float4*)(&As[buf][e0 + 0][kk]);
            float4 a1 = *(const float4*)(&As[buf][e0 + 1][kk]);
            float2 bq0l = *(const float2*)(&Bs[buf][kk + 0][2 * tnn]);
            float2 bq0h = *(const float2*)(&Bs[buf][kk + 0][2 * tnn + 64]);
            float2 bq1l = *(const float2*)(&Bs[buf][kk + 1][2 * tnn]);
            float2 bq1h = *(const float2*)(&Bs[buf][kk + 1][2 * tnn + 64]);
            float2 bq2l = *(const float2*)(&Bs[buf][kk + 2][2 * tnn]);
            float2 bq2h = *(const float2*)(&Bs[buf][kk + 2][2 * tnn + 64]);
            float2 bq3l = *(const float2*)(&Bs[buf][kk + 3][2 * tnn]);
            float2 bq3h = *(const float2*)(&Bs[buf][kk + 3][2 * tnn + 64]);
            // strictly k-ascending fmaf chain per (edge, n)
            acc[0][0] = fmaf(a0.x, bq0l.x, acc[0][0]);
            acc[0][0] = fmaf(a0.y, bq1l.x, acc[0][0]);
            acc[0][0] = fmaf(a0.z, bq2l.x, acc[0][0]);
            acc[0][0] = fmaf(a0.w, bq3l.x, acc[0][0]);
            acc[0][1] = fmaf(a0.x, bq0l.y, acc[0][1]);
            acc[0][1] = fmaf(a0.y, bq1l.y, acc[0][1]);
            acc[0][1] = fmaf(a0.z, bq2l.y, acc[0][1]);
            acc[0][1] = fmaf(a0.w, bq3l.y, acc[0][1]);
            acc[0][2] = fmaf(a0.x, bq0h.x, acc[0][2]);
            acc[0][2] = fmaf(a0.y, bq1h.x, acc[0][2]);
            acc[0][2] = fmaf(a0.z, bq2h.x, acc[0][2]);
            acc[0][2] = fmaf(a0.w, bq3h.x, acc[0][2]);
            acc[0][3] = fmaf(a0.x, bq0h.y, acc[0][3]);
            acc[0][3] = fmaf(a0.y, bq1h.y, acc[0][3]);
            acc[0][3] = fmaf(a0.z, bq2h.y, acc[0][3]);
            acc[0][3] = fmaf(a0.w, bq3h.y, acc[0][3]);
            acc[1][0] = fmaf(a1.x, bq0l.x, acc[1][0]);
            acc[1][0] = fmaf(a1.y, bq1l.x, acc[1][0]);
            acc[1][0] = fmaf(a1.z, bq2l.x, acc[1][0]);
            acc[1][0] = fmaf(a1.w, bq3l.x, acc[1][0]);
            acc[1][1] = fmaf(a1.x, bq0l.y, acc[1][1]);
            acc[1][1] = fmaf(a1.y, bq1l.y, acc[1][1]);
            acc[1][1] = fmaf(a1.z, bq2l.y, acc[1][1]);
            acc[1][1] = fmaf(a1.w, bq3l.y, acc[1][1]);
            acc[1][2] = fmaf(a1.x, bq0h.x, acc[1][2]);
            acc[1][2] = fmaf(a1.y, bq1h.x, acc[1][2]);
            acc[1][2] = fmaf(a1.z, bq2h.x, acc[1][2]);
            acc[1][2] = fmaf(a1.w, bq3h.x, acc[1][2]);
            acc[1][3] = fmaf(a1.x, bq0h.y, acc[1][3]);
            acc[1][3] = fmaf(a1.y, bq1h.y, acc[1][3]);
            acc[1][3] = fmaf(a1.z, bq2h.y, acc[1][3]);
            acc[1][3] = fmaf(a1.w, bq3h.y, acc[1][3]);
        }
        // ---- write next tile into the other buffer (disjoint from reads)
        if (tile + 1 < NT) {
            const int nb = buf ^ 1;
            if (aact) *(float4*)(&As[nb][arow][acol]) = aR;
            Bs[nb][bcol + 0][brow +  0] = bR0.x; Bs[nb][bcol + 1][brow +  0] = bR0.y;
            Bs[nb][bcol + 2][brow +  0] = bR0.z; Bs[nb][bcol + 3][brow +  0] = bR0.w;
            Bs[nb][bcol + 0][brow + 32] = bR1.x; Bs[nb][bcol + 1][brow + 32] = bR1.y;
            Bs[nb][bcol + 2][brow + 32] = bR1.z; Bs[nb][bcol + 3][brow + 32] = bR1.w;
            Bs[nb][bcol + 0][brow + 64] = bR2.x; Bs[nb][bcol + 1][brow + 64] = bR2.y;
            Bs[nb][bcol + 2][brow + 64] = bR2.z; Bs[nb][bcol + 3][brow + 64] = bR2.w;
            Bs[nb][bcol + 0][brow + 96] = bR3.x; Bs[nb][bcol + 1][brow + 96] = bR3.y;
            Bs[nb][bcol + 2][brow + 96] = bR3.z; Bs[nb][bcol + 3][brow + 96] = bR3.w;
        }
        __syncthreads();
    }

    // ---- h = relu(acc + b1), staged to LDS ----
#pragma unroll
    for (int i = 0; i < 2; ++i) {
#pragma unroll
        for (int j = 0; j < 4; ++j) {
            int nn = 2 * tnn + (j & 1) + 64 * (j >> 1);
            float h = fmaxf(acc[i][j] + b1[nn], 0.f);
            hbuf[e0 + i][nn] = h;
        }
    }
    __syncthreads();
    // ---- exact legacy-order second layer: groups of 4 (n=4c..4c+3), then
    //      sequential sum over c=0..31, then +b2, sigmoid ----
    if (t < GBM && b0 + t < n) {
        float s = 0.f;
        for (int c = 0; c < 32; ++c) {
            float p = 0.f;
#pragma unroll
            for (int q = 0; q < 4; ++q)
                p = fmaf(hbuf[t][4 * c + q], W2[4 * c + q], p);
            s += p;
        }
        float logit = s + b2[0];
        float attn  = 1.f / (1.f + expf(-logit));
        wout[elds[t]] = attn;
        ((int*)&rec[b0 + t])[3] = __float_as_int(attn);
    }
}

// ---------------------------------------------------------------------------
// Kernel 7: connected-component labels of the masked-edge graph (compact ids).
// ---------------------------------------------------------------------------
__global__ __launch_bounds__(1024) void label_kernel(
        const int4* __restrict__ rec, const int* __restrict__ nmask,
        int* __restrict__ lbl) {
    extern __shared__ int L[];        // NSLOTS labels + flag at L[NSLOTS]
    int t = threadIdx.x;
    int n = *nmask;
    for (int c = t; c < NSLOTS; c += 1024) L[c] = c;
    __syncthreads();
    for (;;) {
        if (t == 0) L[NSLOTS] = 0;
        __syncthreads();
        for (int e = t; e < n; e += 1024) {
            int4 r = rec[e];
            int a = L[r.x], b = L[r.y];
            if (a < b)      { atomicMin(&L[r.y], a); L[NSLOTS] = 1; }
            else if (b < a) { atomicMin(&L[r.x], b); L[NSLOTS] = 1; }
        }
        __syncthreads();
        if (!L[NSLOTS]) break;
        __syncthreads();
        for (int c = t; c < NSLOTS; c += 1024) {
            int q  = L[c];
            int qq = L[q];
            if (qq < q) L[c] = qq;
        }
        __syncthreads();
    }
    __syncthreads();
    for (int c = t; c < NSLOTS; c += 1024) lbl[c] = L[c];
}

// ---------------------------------------------------------------------------
// Kernel 8: stable grouping of masked edges by CC label (bitonic sort).
// ---------------------------------------------------------------------------
__global__ __launch_bounds__(1024) void sortgroup_kernel(
        const int4* __restrict__ rec, const int* __restrict__ nmask,
        const int* __restrict__ lbl, int4* __restrict__ srec,
        int* __restrict__ compStart, int* __restrict__ ncompOut) {
    extern __shared__ char sm[];
    int2* a          = (int2*)sm;                        // 64 KB
    unsigned char* hd = (unsigned char*)(sm + 65536);    //  8 KB
    int* part        = (int*)(sm + 65536 + 8192);        //  4 KB
    int t = threadIdx.x;
    int n = *nmask;

    for (int i = t; i < SORTN; i += 1024) {
        int key = 0x7FFFFFFF;
        if (i < n) key = (lbl[rec[i].x] << 13) | i;
        a[i] = make_int2(key, i);
    }
    for (int k = 2; k <= SORTN; k <<= 1) {
        for (int j = k >> 1; j > 0; j >>= 1) {
            __syncthreads();
            for (int i = t; i < SORTN; i += 1024) {
                int ixj = i ^ j;
                if (ixj > i) {
                    int2 ai = a[i], aj = a[ixj];
                    bool up = ((i & k) == 0);
                    if ((ai.x > aj.x) == up) { a[i] = aj; a[ixj] = ai; }
                }
            }
        }
    }
    __syncthreads();
    for (int i = t; i < SORTN; i += 1024) {
        int h = 0;
        if (i < n) {
            srec[i] = rec[a[i].y];
            int l  = a[i].x >> 13;
            int lp = (i == 0) ? -1 : (a[i - 1].x >> 13);
            h = (l != lp) ? 1 : 0;
        }
        hd[i] = (unsigned char)h;
    }
    __syncthreads();
    int base = t * 8;
    int s = 0;
#pragma unroll
    for (int q = 0; q < 8; ++q) s += hd[base + q];
    part[t] = s;
    __syncthreads();
    for (int off = 1; off < 1024; off <<= 1) {
        int mine  = part[t];
        int other = (t >= off) ? part[t - off] : 0;
        __syncthreads();
        part[t] = mine + other;
        __syncthreads();
    }
    int total = part[1023];
    int run = part[t] - s;
#pragma unroll
    for (int q = 0; q < 8; ++q) {
        if (hd[base + q]) { compStart[run] = base + q; ++run; }
    }
    if (t == 0)    *ncompOut = total;
    if (t == 1023) compStart[total] = n;
}

// ---------------------------------------------------------------------------
// Kernel 9: exact union-find, parallel over connected components.
// ---------------------------------------------------------------------------
__global__ __launch_bounds__(256) void uf_kernel(
        const int4* __restrict__ srec, const int* __restrict__ ncompPtr,
        const int* __restrict__ compStart,
        const int* __restrict__ orig, const float* __restrict__ rin,
        int* __restrict__ gpar, float* __restrict__ grank) {
    extern __shared__ char smem[];
    int2* nd = (int2*)smem;    // 128 KB {parent, rank-bits}
    int* ndw = (int*)smem;
    int t = threadIdx.x;
    for (int c = t; c < NSLOTS; c += 256) {
        int o = orig[c];
        float r = (o >= 0) ? rin[o] : 1.0f;
        nd[c] = make_int2(c, __float_as_int(r));
    }
    __syncthreads();

    int ncomp = *ncompPtr;
    for (int c = t; c < ncomp; c += 256) {
        int s  = compStart[c];
        int en = compStart[c + 1];
        for (int j = s; j < en; ++j) {
            int4 r = srec[j];
            int x = r.x, y = r.y;
            float wi = __int_as_float(r.w);
            int p;
            int rx = x;
            while ((p = ndw[rx * 2]) != rx) rx = p;
            int j2 = x;
            while ((p = ndw[j2 * 2]) != rx) { ndw[j2 * 2] = rx; j2 = p; }
            int ry = y;
            while ((p = ndw[ry * 2]) != ry) ry = p;
            j2 = y;
            while ((p = ndw[j2 * 2]) != ry) { ndw[j2 * 2] = ry; j2 = p; }
            if (rx != ry) {
                float ka = __int_as_float(ndw[rx * 2 + 1]);
                float kb = __int_as_float(ndw[ry * 2 + 1]);
                bool bx = ka > kb;
                int big = bx ? rx : ry, small = bx ? ry : rx;
                float nr = bx ? (ka + kb * wi) : (kb + ka * wi);
                ndw[small * 2]   = big;
                ndw[big * 2 + 1] = __float_as_int(nr);
            }
        }
    }
    __syncthreads();
    for (int c = t; c < NSLOTS; c += 256) {
        int2 v = nd[c];
        gpar[c] = v.x;
        grank[c] = __int_as_float(v.y);
    }
}

// ---------------------------------------------------------------------------
// Kernel 10: finalize — per node, claimed -> compact result, else input copy.
// ---------------------------------------------------------------------------
__global__ void finalize_kernel(const int* __restrict__ pin, const float* __restrict__ rin,
                                const int* __restrict__ fo, const int* __restrict__ orig,
                                const int* __restrict__ gpar, const float* __restrict__ grank,
                                float* __restrict__ pout, float* __restrict__ rout) {
    int i = blockIdx.x * blockDim.x + threadIdx.x;
    if (i >= N_NODES) return;
    int c = fo[i];
    float pv, rv;
    if (c != 0x7FFFFFFF) {
        pv = (float)orig[gpar[c]];
        rv = grank[c];
    } else {
        pv = (float)pin[i];
        rv = rin[i];
    }
    pout[i] = pv;
    rout[i] = rv;
}

// ---------------------------------------------------------------------------
extern "C" void kernel_launch(void* const* d_in, const int* in_sizes, int n_in,
                              void* d_out, int out_size, void* d_ws, size_t ws_size,
                              hipStream_t stream) {
    const int*   x_idx = (const int*)d_in[0];
    const int*   y_idx = (const int*)d_in[1];
    const float* xf    = (const float*)d_in[2];
    const float* yf    = (const float*)d_in[3];
    const float* W1    = (const float*)d_in[4];
    const float* b1    = (const float*)d_in[5];
    const float* W2    = (const float*)d_in[6];
    const float* b2    = (const float*)d_in[7];
    const int*   pin   = (const int*)d_in[8];
    const float* rin   = (const float*)d_in[9];

    float* out   = (float*)d_out;
    float* w_out = out;                        // [E]
    float* pout  = out + E_EDGES;              // [N]
    float* rout  = out + E_EDGES + N_NODES;    // [N]

    char* ws = (char*)d_ws;
    float* sim_ws  = (float*)(ws + 0);         //  32768 B
    int*   fo      = (int*)  (ws + 32768);     // 400000 B
    int*   orig    = (int*)  (ws + 432768);    //  65536 B
    int4*  rec     = (int4*) (ws + 498304);    // 131136 B  (8192+4 recs)
    int*   nmask   = (int*)  (ws + 629440);    //     64 B
    int*   gpar    = (int*)  (ws + 629504);    //  65536 B
    float* grank   = (float*)(ws + 695040);    //  65536 B
    int4*  srec    = (int4*) (ws + 760576);    // 131072 B
    int*   compSt  = (int*)  (ws + 891648);    //  32772 B (8193 ints)
    int*   ncomp   = (int*)  (ws + 924424);    //      4 B  -> total ~924 KB
    int*   lbl     = gpar;   // overlay: lbl consumed before uf writes gpar

    // 1) cosine sim
    sim_kernel<<<(E_EDGES * 64) / 256, 256, 0, stream>>>(xf, yf, sim_ws);
    // 2) compact-id mapping + zero w
    int g = (N_NODES + 255) / 256;
    initmap_kernel<<<g, 256, 0, stream>>>(fo, orig, w_out);
    claim_kernel<<<NSLOTS / 256, 256, 0, stream>>>(x_idx, y_idx, fo);
    orig_kernel<<<NSLOTS / 256, 256, 0, stream>>>(x_idx, y_idx, fo, orig);
    // 3) masked-edge compaction (records + padding)
    maskscan_kernel<<<1, 256, 0, stream>>>(x_idx, y_idx, fo, sim_ws, rec, nmask);
    // 4) gate MLP v2 over masked edges only (fills rec.w)
    gate_kernel<<<E_EDGES / GBM, 256, 0, stream>>>(xf, yf, W1, b1, W2, b2, rec, nmask, w_out);
    // 5) CC labels of masked-edge graph (deterministic min-label fixpoint)
    label_kernel<<<1, 1024, (NSLOTS + 1) * sizeof(int), stream>>>(rec, nmask, lbl);
    // 6) stable per-CC grouping (bitonic sort + boundaries)
    sortgroup_kernel<<<1, 1024, 65536 + 8192 + 4096, stream>>>(rec, nmask, lbl,
                                                               srec, compSt, ncomp);
    // 7) exact UF, parallel over components (LDS 128 KB)
    uf_kernel<<<1, 256, 131072, stream>>>(srec, ncomp, compSt, orig, rin, gpar, grank);
    // 8) finalize outputs (base copy + compact scatter fused)
    finalize_kernel<<<g, 256, 0, stream>>>(pin, rin, fo, orig, gpar, grank, pout, rout);
}

// Round 12
// 397.948 us; speedup vs baseline: 3.5897x; 1.1198x over previous
//
#include <hip/hip_runtime.h>
#include <math.h>

#define E_EDGES 8192
#define D_FEAT 2048
#define K2 4096   // 2*D
#define H_DIM 128
#define N_NODES 100000
#define SIM_TH 0.7f
#define NSLOTS (2 * E_EDGES)   // 16384 compact slots
#define SORTN 8192
#define GBM 16                 // gate edges per block

// ---------------------------------------------------------------------------
// Kernel 1: cosine similarity per edge. One wave (64 lanes) per edge.
// ---------------------------------------------------------------------------
__global__ __launch_bounds__(256) void sim_kernel(const float* __restrict__ xf,
                                                  const float* __restrict__ yf,
                                                  float* __restrict__ sim) {
    int gid  = blockIdx.x * blockDim.x + threadIdx.x;
    int wave = gid >> 6;
    int lane = threadIdx.x & 63;
    if (wave >= E_EDGES) return;
    const float4* xp = (const float4*)(xf + (size_t)wave * D_FEAT);
    const float4* yp = (const float4*)(yf + (size_t)wave * D_FEAT);
    float dot = 0.f, xx = 0.f, yy = 0.f;
#pragma unroll
    for (int j = 0; j < 8; ++j) {
        float4 a = xp[lane + j * 64];
        float4 b = yp[lane + j * 64];
        dot += a.x * b.x + a.y * b.y + a.z * b.z + a.w * b.w;
        xx  += a.x * a.x + a.y * a.y + a.z * a.z + a.w * a.w;
        yy  += b.x * b.x + b.y * b.y + b.z * b.z + b.w * b.w;
    }
#pragma unroll
    for (int off = 32; off; off >>= 1) {
        dot += __shfl_xor(dot, off);
        xx  += __shfl_xor(xx, off);
        yy  += __shfl_xor(yy, off);
    }
    if (lane == 0) {
        float nx = fmaxf(sqrtf(xx), 1e-8f);
        float ny = fmaxf(sqrtf(yy), 1e-8f);
        sim[wave] = dot / (nx * ny);
    }
}

// ---------------------------------------------------------------------------
// Kernel 2: init fo (=INT_MAX), orig (=-1), zero w output.
// ---------------------------------------------------------------------------
__global__ void initmap_kernel(int* __restrict__ fo, int* __restrict__ orig,
                               float* __restrict__ wout) {
    int i = blockIdx.x * blockDim.x + threadIdx.x;
    if (i < N_NODES) fo[i] = 0x7FFFFFFF;
    if (i < NSLOTS)  orig[i] = -1;
    if (i < E_EDGES) wout[i] = 0.f;
}

// ---------------------------------------------------------------------------
// Kernel 3: claim compact slot = first occurrence index in x0,y0,x1,y1,...
// ---------------------------------------------------------------------------
__global__ void claim_kernel(const int* __restrict__ x_idx, const int* __restrict__ y_idx,
                             int* __restrict__ fo) {
    int i = blockIdx.x * blockDim.x + threadIdx.x;
    if (i >= NSLOTS) return;
    int e = i >> 1;
    int v = (i & 1) ? y_idx[e] : x_idx[e];
    atomicMin(&fo[v], i);
}

// ---------------------------------------------------------------------------
// Kernel 4: orig[slot] = node for claimed slots.
// ---------------------------------------------------------------------------
__global__ void orig_kernel(const int* __restrict__ x_idx, const int* __restrict__ y_idx,
                            const int* __restrict__ fo, int* __restrict__ orig) {
    int i = blockIdx.x * blockDim.x + threadIdx.x;
    if (i >= NSLOTS) return;
    int e = i >> 1;
    int v = (i & 1) ? y_idx[e] : x_idx[e];
    if (fo[v] == i) orig[i] = v;
}

// ---------------------------------------------------------------------------
// Kernel 5: order-preserving compaction of masked edges into records
//           rec = {cx, cy, eidx, (w filled later by gate)} + 4 zero pads.
// ---------------------------------------------------------------------------
__global__ __launch_bounds__(256) void maskscan_kernel(
        const int* __restrict__ x_idx, const int* __restrict__ y_idx,
        const int* __restrict__ fo, const float* __restrict__ sim,
        int4* __restrict__ rec, int* __restrict__ nmask) {
    __shared__ int partial[256];
    int t = threadIdx.x;
    int cnt = 0;
    for (int j = 0; j < 32; ++j) {
        int e = t * 32 + j;
        cnt += (sim[e] >= SIM_TH) ? 1 : 0;
    }
    partial[t] = cnt;
    __syncthreads();
    for (int off = 1; off < 256; off <<= 1) {
        int mine  = partial[t];
        int other = (t >= off) ? partial[t - off] : 0;
        __syncthreads();
        partial[t] = mine + other;
        __syncthreads();
    }
    int pos = partial[t] - cnt;
    if (t == 255) {
        int nn = partial[255];
        *nmask = nn;
        for (int j = 0; j < 4; ++j) rec[nn + j] = make_int4(0, 0, 0, 0);
    }
    for (int j = 0; j < 32; ++j) {
        int e = t * 32 + j;
        if (sim[e] >= SIM_TH) {
            int4 r;
            r.x = fo[x_idx[e]];
            r.y = fo[y_idx[e]];
            r.z = e;
            r.w = 0;
            rec[pos++] = r;
        }
    }
}

// ---------------------------------------------------------------------------
// Kernel 6: gate MLP v3 over MASKED edges. fp32 GEMM M=n, N=128, K=4096.
//   Lane = n column (n and n+64), wave = 4 edges: A reads are wave-uniform
//   (LDS broadcast, free), B reads are per-lane b32 on pitch-33 rows
//   (2-way banks, free).  ~1 B/fma on the per-lane LDS path (3x less than
//   v2).  Double-buffered, reg-prefetched staging.  Accumulation strictly
//   k-ascending per (e,n); legacy-order epilogue -> bit-identical outputs.
// ---------------------------------------------------------------------------
__global__ __launch_bounds__(256) void gate_kernel(
        const float* __restrict__ xf, const float* __restrict__ yf,
        const float* __restrict__ W1, const float* __restrict__ b1,
        const float* __restrict__ W2, const float* __restrict__ b2,
        int4* __restrict__ rec, const int* __restrict__ nmask,
        float* __restrict__ wout) {
    __shared__ float As[2][GBM][32];       //  4 KB
    __shared__ float Bs[2][H_DIM][33];     // 33.8 KB (pitch 33: banks spread)
    __shared__ float hbuf[GBM][132];       //  8.4 KB
    __shared__ int   elds[GBM];

    int n  = *nmask;
    int b0 = blockIdx.x * GBM;
    if (b0 >= n) return;

    int t = threadIdx.x;
    if (t < GBM) {
        int idx = b0 + t;
        elds[t] = (idx < n) ? rec[idx].z : rec[b0].z;
    }
    __syncthreads();

    // staging assignments
    const int  arow = t >> 3;            // rows 0..15 for t<128
    const int  acol = (t & 7) * 4;
    const bool aact = (t < 128);
    const int  brow = t >> 3;            // W1 rows brow + 32r
    const int  bcol = (t & 7) * 4;

    const float* xrow = xf + (size_t)elds[aact ? arow : 0] * D_FEAT + acol;
    const float* yrow = yf + (size_t)elds[aact ? arow : 0] * D_FEAT + acol;
    const float* w1p0 = W1 + (size_t)(brow +  0) * K2 + bcol;
    const float* w1p1 = W1 + (size_t)(brow + 32) * K2 + bcol;
    const float* w1p2 = W1 + (size_t)(brow + 64) * K2 + bcol;
    const float* w1p3 = W1 + (size_t)(brow + 96) * K2 + bcol;

    float4 aR = make_float4(0.f, 0.f, 0.f, 0.f);
    float4 bR0, bR1, bR2, bR3;

    // ---- prologue: load + store tile 0 ----
    {
        if (aact) aR = *(const float4*)(xrow + 0);
        bR0 = *(const float4*)(w1p0 + 0);
        bR1 = *(const float4*)(w1p1 + 0);
        bR2 = *(const float4*)(w1p2 + 0);
        bR3 = *(const float4*)(w1p3 + 0);
        if (aact) *(float4*)(&As[0][arow][acol]) = aR;
        Bs[0][brow +  0][bcol + 0] = bR0.x; Bs[0][brow +  0][bcol + 1] = bR0.y;
        Bs[0][brow +  0][bcol + 2] = bR0.z; Bs[0][brow +  0][bcol + 3] = bR0.w;
        Bs[0][brow + 32][bcol + 0] = bR1.x; Bs[0][brow + 32][bcol + 1] = bR1.y;
        Bs[0][brow + 32][bcol + 2] = bR1.z; Bs[0][brow + 32][bcol + 3] = bR1.w;
        Bs[0][brow + 64][bcol + 0] = bR2.x; Bs[0][brow + 64][bcol + 1] = bR2.y;
        Bs[0][brow + 64][bcol + 2] = bR2.z; Bs[0][brow + 64][bcol + 3] = bR2.w;
        Bs[0][brow + 96][bcol + 0] = bR3.x; Bs[0][brow + 96][bcol + 1] = bR3.y;
        Bs[0][brow + 96][bcol + 2] = bR3.z; Bs[0][brow + 96][bcol + 3] = bR3.w;
    }
    __syncthreads();

    const int eb = (t >> 6) * 4;         // this wave's 4 edge rows
    const int ln = t & 63;               // n = ln and ln+64
    float acc[4][2] = {{0.f,0.f},{0.f,0.f},{0.f,0.f},{0.f,0.f}};

    const int NT = K2 / 32;              // 128 tiles
    for (int tile = 0; tile < NT; ++tile) {
        const int buf = tile & 1;
        // ---- issue next tile's global loads (hidden under compute) ----
        if (tile + 1 < NT) {
            int k0 = (tile + 1) * 32;
            if (aact) {
                const float* ap = (k0 < D_FEAT) ? (xrow + k0) : (yrow + (k0 - D_FEAT));
                aR = *(const float4*)ap;
            }
            bR0 = *(const float4*)(w1p0 + k0);
            bR1 = *(const float4*)(w1p1 + k0);
            bR2 = *(const float4*)(w1p2 + k0);
            bR3 = *(const float4*)(w1p3 + k0);
        }
        // ---- compute current tile ----
#pragma unroll
        for (int kk = 0; kk < 32; kk += 4) {
            float4 a0 = *(const float4*)(&As[buf][eb + 0][kk]);   // wave-uniform
            float4 a1 = *(const float4*)(&As[buf][eb + 1][kk]);
            float4 a2 = *(const float4*)(&As[buf][eb + 2][kk]);
            float4 a3 = *(const float4*)(&As[buf][eb + 3][kk]);
            float bl0 = Bs[buf][ln][kk + 0];
            float bl1 = Bs[buf][ln][kk + 1];
            float bl2 = Bs[buf][ln][kk + 2];
            float bl3 = Bs[buf][ln][kk + 3];
            float bh0 = Bs[buf][ln + 64][kk + 0];
            float bh1 = Bs[buf][ln + 64][kk + 1];
            float bh2 = Bs[buf][ln + 64][kk + 2];
            float bh3 = Bs[buf][ln + 64][kk + 3];
            // strictly k-ascending fmaf chain per (edge, n)
            acc[0][0] = fmaf(a0.x, bl0, acc[0][0]);
            acc[0][0] = fmaf(a0.y, bl1, acc[0][0]);
            acc[0][0] = fmaf(a0.z, bl2, acc[0][0]);
            acc[0][0] = fmaf(a0.w, bl3, acc[0][0]);
            acc[0][1] = fmaf(a0.x, bh0, acc[0][1]);
            acc[0][1] = fmaf(a0.y, bh1, acc[0][1]);
            acc[0][1] = fmaf(a0.z, bh2, acc[0][1]);
            acc[0][1] = fmaf(a0.w, bh3, acc[0][1]);
            acc[1][0] = fmaf(a1.x, bl0, acc[1][0]);
            acc[1][0] = fmaf(a1.y, bl1, acc[1][0]);
            acc[1][0] = fmaf(a1.z, bl2, acc[1][0]);
            acc[1][0] = fmaf(a1.w, bl3, acc[1][0]);
            acc[1][1] = fmaf(a1.x, bh0, acc[1][1]);
            acc[1][1] = fmaf(a1.y, bh1, acc[1][1]);
            acc[1][1] = fmaf(a1.z, bh2, acc[1][1]);
            acc[1][1] = fmaf(a1.w, bh3, acc[1][1]);
            acc[2][0] = fmaf(a2.x, bl0, acc[2][0]);
            acc[2][0] = fmaf(a2.y, bl1, acc[2][0]);
            acc[2][0] = fmaf(a2.z, bl2, acc[2][0]);
            acc[2][0] = fmaf(a2.w, bl3, acc[2][0]);
            acc[2][1] = fmaf(a2.x, bh0, acc[2][1]);
            acc[2][1] = fmaf(a2.y, bh1, acc[2][1]);
            acc[2][1] = fmaf(a2.z, bh2, acc[2][1]);
            acc[2][1] = fmaf(a2.w, bh3, acc[2][1]);
            acc[3][0] = fmaf(a3.x, bl0, acc[3][0]);
            acc[3][0] = fmaf(a3.y, bl1, acc[3][0]);
            acc[3][0] = fmaf(a3.z, bl2, acc[3][0]);
            acc[3][0] = fmaf(a3.w, bl3, acc[3][0]);
            acc[3][1] = fmaf(a3.x, bh0, acc[3][1]);
            acc[3][1] = fmaf(a3.y, bh1, acc[3][1]);
            acc[3][1] = fmaf(a3.z, bh2, acc[3][1]);
            acc[3][1] = fmaf(a3.w, bh3, acc[3][1]);
        }
        // ---- write next tile into the other buffer ----
        if (tile + 1 < NT) {
            const int nb = buf ^ 1;
            if (aact) *(float4*)(&As[nb][arow][acol]) = aR;
            Bs[nb][brow +  0][bcol + 0] = bR0.x; Bs[nb][brow +  0][bcol + 1] = bR0.y;
            Bs[nb][brow +  0][bcol + 2] = bR0.z; Bs[nb][brow +  0][bcol + 3] = bR0.w;
            Bs[nb][brow + 32][bcol + 0] = bR1.x; Bs[nb][brow + 32][bcol + 1] = bR1.y;
            Bs[nb][brow + 32][bcol + 2] = bR1.z; Bs[nb][brow + 32][bcol + 3] = bR1.w;
            Bs[nb][brow + 64][bcol + 0] = bR2.x; Bs[nb][brow + 64][bcol + 1] = bR2.y;
            Bs[nb][brow + 64][bcol + 2] = bR2.z; Bs[nb][brow + 64][bcol + 3] = bR2.w;
            Bs[nb][brow + 96][bcol + 0] = bR3.x; Bs[nb][brow + 96][bcol + 1] = bR3.y;
            Bs[nb][brow + 96][bcol + 2] = bR3.z; Bs[nb][brow + 96][bcol + 3] = bR3.w;
        }
        __syncthreads();
    }

    // ---- h = relu(acc + b1) into hbuf ----
#pragma unroll
    for (int j = 0; j < 4; ++j) {
        hbuf[eb + j][ln]      = fmaxf(acc[j][0] + b1[ln], 0.f);
        hbuf[eb + j][ln + 64] = fmaxf(acc[j][1] + b1[ln + 64], 0.f);
    }
    __syncthreads();
    // ---- exact legacy-order second layer ----
    if (t < GBM && b0 + t < n) {
        float s = 0.f;
        for (int c = 0; c < 32; ++c) {
            float p = 0.f;
#pragma unroll
            for (int q = 0; q < 4; ++q)
                p = fmaf(hbuf[t][4 * c + q], W2[4 * c + q], p);
            s += p;
        }
        float logit = s + b2[0];
        float attn  = 1.f / (1.f + expf(-logit));
        wout[elds[t]] = attn;
        ((int*)&rec[b0 + t])[3] = __float_as_int(attn);
    }
}

// ---------------------------------------------------------------------------
// Kernel 7: connected-component labels of the masked-edge graph (compact ids).
// ---------------------------------------------------------------------------
__global__ __launch_bounds__(1024) void label_kernel(
        const int4* __restrict__ rec, const int* __restrict__ nmask,
        int* __restrict__ lbl) {
    extern __shared__ int L[];        // NSLOTS labels + flag at L[NSLOTS]
    int t = threadIdx.x;
    int n = *nmask;
    for (int c = t; c < NSLOTS; c += 1024) L[c] = c;
    __syncthreads();
    for (;;) {
        if (t == 0) L[NSLOTS] = 0;
        __syncthreads();
        for (int e = t; e < n; e += 1024) {
            int4 r = rec[e];
            int a = L[r.x], b = L[r.y];
            if (a < b)      { atomicMin(&L[r.y], a); L[NSLOTS] = 1; }
            else if (b < a) { atomicMin(&L[r.x], b); L[NSLOTS] = 1; }
        }
        __syncthreads();
        if (!L[NSLOTS]) break;
        __syncthreads();
        for (int c = t; c < NSLOTS; c += 1024) {
            int q  = L[c];
            int qq = L[q];
            if (qq < q) L[c] = qq;
        }
        __syncthreads();
    }
    __syncthreads();
    for (int c = t; c < NSLOTS; c += 1024) lbl[c] = L[c];
}

// ---------------------------------------------------------------------------
// Kernel 8: stable grouping of masked edges by CC label (bitonic sort).
// ---------------------------------------------------------------------------
__global__ __launch_bounds__(1024) void sortgroup_kernel(
        const int4* __restrict__ rec, const int* __restrict__ nmask,
        const int* __restrict__ lbl, int4* __restrict__ srec,
        int* __restrict__ compStart, int* __restrict__ ncompOut) {
    extern __shared__ char sm[];
    int2* a          = (int2*)sm;                        // 64 KB
    unsigned char* hd = (unsigned char*)(sm + 65536);    //  8 KB
    int* part        = (int*)(sm + 65536 + 8192);        //  4 KB
    int t = threadIdx.x;
    int n = *nmask;

    for (int i = t; i < SORTN; i += 1024) {
        int key = 0x7FFFFFFF;
        if (i < n) key = (lbl[rec[i].x] << 13) | i;
        a[i] = make_int2(key, i);
    }
    for (int k = 2; k <= SORTN; k <<= 1) {
        for (int j = k >> 1; j > 0; j >>= 1) {
            __syncthreads();
            for (int i = t; i < SORTN; i += 1024) {
                int ixj = i ^ j;
                if (ixj > i) {
                    int2 ai = a[i], aj = a[ixj];
                    bool up = ((i & k) == 0);
                    if ((ai.x > aj.x) == up) { a[i] = aj; a[ixj] = ai; }
                }
            }
        }
    }
    __syncthreads();
    for (int i = t; i < SORTN; i += 1024) {
        int h = 0;
        if (i < n) {
            srec[i] = rec[a[i].y];
            int l  = a[i].x >> 13;
            int lp = (i == 0) ? -1 : (a[i - 1].x >> 13);
            h = (l != lp) ? 1 : 0;
        }
        hd[i] = (unsigned char)h;
    }
    __syncthreads();
    int base = t * 8;
    int s = 0;
#pragma unroll
    for (int q = 0; q < 8; ++q) s += hd[base + q];
    part[t] = s;
    __syncthreads();
    for (int off = 1; off < 1024; off <<= 1) {
        int mine  = part[t];
        int other = (t >= off) ? part[t - off] : 0;
        __syncthreads();
        part[t] = mine + other;
        __syncthreads();
    }
    int total = part[1023];
    int run = part[t] - s;
#pragma unroll
    for (int q = 0; q < 8; ++q) {
        if (hd[base + q]) { compStart[run] = base + q; ++run; }
    }
    if (t == 0)    *ncompOut = total;
    if (t == 1023) compStart[total] = n;
}

// ---------------------------------------------------------------------------
// Kernel 9: exact union-find, parallel over connected components.
// ---------------------------------------------------------------------------
__global__ __launch_bounds__(256) void uf_kernel(
        const int4* __restrict__ srec, const int* __restrict__ ncompPtr,
        const int* __restrict__ compStart,
        const int* __restrict__ orig, const float* __restrict__ rin,
        int* __restrict__ gpar, float* __restrict__ grank) {
    extern __shared__ char smem[];
    int2* nd = (int2*)smem;    // 128 KB {parent, rank-bits}
    int* ndw = (int*)smem;
    int t = threadIdx.x;
    for (int c = t; c < NSLOTS; c += 256) {
        int o = orig[c];
        float r = (o >= 0) ? rin[o] : 1.0f;
        nd[c] = make_int2(c, __float_as_int(r));
    }
    __syncthreads();

    int ncomp = *ncompPtr;
    for (int c = t; c < ncomp; c += 256) {
        int s  = compStart[c];
        int en = compStart[c + 1];
        for (int j = s; j < en; ++j) {
            int4 r = srec[j];
            int x = r.x, y = r.y;
            float wi = __int_as_float(r.w);
            int p;
            int rx = x;
            while ((p = ndw[rx * 2]) != rx) rx = p;
            int j2 = x;
            while ((p = ndw[j2 * 2]) != rx) { ndw[j2 * 2] = rx; j2 = p; }
            int ry = y;
            while ((p = ndw[ry * 2]) != ry) ry = p;
            j2 = y;
            while ((p = ndw[j2 * 2]) != ry) { ndw[j2 * 2] = ry; j2 = p; }
            if (rx != ry) {
                float ka = __int_as_float(ndw[rx * 2 + 1]);
                float kb = __int_as_float(ndw[ry * 2 + 1]);
                bool bx = ka > kb;
                int big = bx ? rx : ry, small = bx ? ry : rx;
                float nr = bx ? (ka + kb * wi) : (kb + ka * wi);
                ndw[small * 2]   = big;
                ndw[big * 2 + 1] = __float_as_int(nr);
            }
        }
    }
    __syncthreads();
    for (int c = t; c < NSLOTS; c += 256) {
        int2 v = nd[c];
        gpar[c] = v.x;
        grank[c] = __int_as_float(v.y);
    }
}

// ---------------------------------------------------------------------------
// Kernel 10: finalize — per node, claimed -> compact result, else input copy.
// ---------------------------------------------------------------------------
__global__ void finalize_kernel(const int* __restrict__ pin, const float* __restrict__ rin,
                                const int* __restrict__ fo, const int* __restrict__ orig,
                                const int* __restrict__ gpar, const float* __restrict__ grank,
                                float* __restrict__ pout, float* __restrict__ rout) {
    int i = blockIdx.x * blockDim.x + threadIdx.x;
    if (i >= N_NODES) return;
    int c = fo[i];
    float pv, rv;
    if (c != 0x7FFFFFFF) {
        pv = (float)orig[gpar[c]];
        rv = grank[c];
    } else {
        pv = (float)pin[i];
        rv = rin[i];
    }
    pout[i] = pv;
    rout[i] = rv;
}

// ---------------------------------------------------------------------------
extern "C" void kernel_launch(void* const* d_in, const int* in_sizes, int n_in,
                              void* d_out, int out_size, void* d_ws, size_t ws_size,
                              hipStream_t stream) {
    const int*   x_idx = (const int*)d_in[0];
    const int*   y_idx = (const int*)d_in[1];
    const float* xf    = (const float*)d_in[2];
    const float* yf    = (const float*)d_in[3];
    const float* W1    = (const float*)d_in[4];
    const float* b1    = (const float*)d_in[5];
    const float* W2    = (const float*)d_in[6];
    const float* b2    = (const float*)d_in[7];
    const int*   pin   = (const int*)d_in[8];
    const float* rin   = (const float*)d_in[9];

    float* out   = (float*)d_out;
    float* w_out = out;                        // [E]
    float* pout  = out + E_EDGES;              // [N]
    float* rout  = out + E_EDGES + N_NODES;    // [N]

    char* ws = (char*)d_ws;
    float* sim_ws  = (float*)(ws + 0);         //  32768 B
    int*   fo      = (int*)  (ws + 32768);     // 400000 B
    int*   orig    = (int*)  (ws + 432768);    //  65536 B
    int4*  rec     = (int4*) (ws + 498304);    // 131136 B  (8192+4 recs)
    int*   nmask   = (int*)  (ws + 629440);    //     64 B
    int*   gpar    = (int*)  (ws + 629504);    //  65536 B
    float* grank   = (float*)(ws + 695040);    //  65536 B
    int4*  srec    = (int4*) (ws + 760576);    // 131072 B
    int*   compSt  = (int*)  (ws + 891648);    //  32772 B (8193 ints)
    int*   ncomp   = (int*)  (ws + 924424);    //      4 B  -> total ~924 KB
    int*   lbl     = gpar;   // overlay: lbl consumed before uf writes gpar

    // 1) cosine sim
    sim_kernel<<<(E_EDGES * 64) / 256, 256, 0, stream>>>(xf, yf, sim_ws);
    // 2) compact-id mapping + zero w
    int g = (N_NODES + 255) / 256;
    initmap_kernel<<<g, 256, 0, stream>>>(fo, orig, w_out);
    claim_kernel<<<NSLOTS / 256, 256, 0, stream>>>(x_idx, y_idx, fo);
    orig_kernel<<<NSLOTS / 256, 256, 0, stream>>>(x_idx, y_idx, fo, orig);
    // 3) masked-edge compaction (records + padding)
    maskscan_kernel<<<1, 256, 0, stream>>>(x_idx, y_idx, fo, sim_ws, rec, nmask);
    // 4) gate MLP v3 over masked edges only (fills rec.w)
    gate_kernel<<<E_EDGES / GBM, 256, 0, stream>>>(xf, yf, W1, b1, W2, b2, rec, nmask, w_out);
    // 5) CC labels of masked-edge graph (deterministic min-label fixpoint)
    label_kernel<<<1, 1024, (NSLOTS + 1) * sizeof(int), stream>>>(rec, nmask, lbl);
    // 6) stable per-CC grouping (bitonic sort + boundaries)
    sortgroup_kernel<<<1, 1024, 65536 + 8192 + 4096, stream>>>(rec, nmask, lbl,
                                                               srec, compSt, ncomp);
    // 7) exact UF, parallel over components (LDS 128 KB)
    uf_kernel<<<1, 256, 131072, stream>>>(srec, ncomp, compSt, orig, rin, gpar, grank);
    // 8) finalize outputs (base copy + compact scatter fused)
    finalize_kernel<<<g, 256, 0, stream>>>(pin, rin, fo, orig, gpar, grank, pout, rout);
}